// Round 9
// baseline (683.248 us; speedup 1.0000x reference)
//
#include <hip/hip_runtime.h>

#define N_TOK 8192
#define DIM   2048
#define FFN   1408

// ---------- ws layout (bytes); top = 231,735,552 ----------
// hp  [0, 51.2M)           gemm_gu w -> gemm_down r
// xb  [51.2M, 84.7M)       router w -> gather r      (dead before pack_gu)
// p1  [51.2M, 143.5M)      pack_gu w -> gemm_gu r    (overwrites dead xb)
// p2  [51.2M, 97.3M)       pack_d (after gemm_gu) w -> gemm_down r (aliases dead p1)
// eo  [97.3M, 231.5M)      gemm_down w -> combine r  (aliases dead p1-tail + xgp)
// xgp [143.5M, 217.9M)     gather w -> gemm_gu r
#define HP_OFF  0ull                   // 71 tiles x 44 j x 16384
#define XB_OFF  51183616ull            // bf16 x [8192][2048]
#define P1_OFF  51183616ull            // 8 x 11 x 64 x 16384
#define P2_OFF  51183616ull            // 8 x 8 x 44 x 16384
#define EO_OFF  97320960ull            // f32 [16384][2048]
#define XGP_OFF 143458304ull           // 71 tiles x 64 j x 16384
#define LPK_OFF 231538688ull           // [16384] int
#define TI_OFF  231604224ull           // [8192] int
#define TW_OFF  231636992ull           // [8192] f32
#define TP_OFF  231669760ull           // [8192] int2
#define ST_OFF  231735296ull           // cnt8 cur8 abase8 tbase8 ttot ; psum u64[8] @+192

typedef __bf16 bf16x8 __attribute__((ext_vector_type(8)));
typedef float  f32x4  __attribute__((ext_vector_type(4)));
typedef int    int4v  __attribute__((ext_vector_type(4)));
typedef __attribute__((address_space(1))) void as1_void;
typedef __attribute__((address_space(3))) void as3_void;

__device__ __forceinline__ void gload16(const void* g, void* l) {
  __builtin_amdgcn_global_load_lds((as1_void*)g, (as3_void*)l, 16, 0, 0);
}

__device__ __forceinline__ ushort f2bf(float f) {
  unsigned u = __builtin_bit_cast(unsigned, f);
  u += 0x7FFFu + ((u >> 16) & 1u);
  return (ushort)(u >> 16);
}

__device__ __forceinline__ int4v dsread(int addr) {
  int4v d;
  asm volatile("ds_read_b128 %0, %1" : "=v"(d) : "v"(addr));
  return d;
}

#define WAITL() do { asm volatile("s_waitcnt lgkmcnt(0)" ::: "memory"); \
                     __builtin_amdgcn_sched_barrier(0); } while (0)
#define BAR()   __builtin_amdgcn_s_barrier()
#define MFMA16(a, b, c) __builtin_amdgcn_mfma_f32_16x16x32_bf16(a, b, c, 0, 0, 0)
#define BC(x) __builtin_bit_cast(bf16x8, x)

// 16KB unit = 256 rows x 32 k bf16. Piece (row, s): q=row>>1 (0..127),
// p = (((row&1)<<2)|s) ^ (q&7); byte = q*128 + p*16.
__device__ __forceinline__ int swz(int row, int s) {
  int q = row >> 1;
  int p = (((row & 1) << 2) | s) ^ (q & 7);
  return q * 128 + p * 16;
}

// ---------------- router (+ x -> bf16) ----------------
__global__ __launch_bounds__(256) void router_kernel(
    const float* __restrict__ x, const float* __restrict__ rw,
    ushort* __restrict__ xb, int* __restrict__ topi, float* __restrict__ topw,
    int* __restrict__ cnt, unsigned long long* __restrict__ psum)
{
  int tid = threadIdx.x, lane = tid & 63, wv = tid >> 6;
  __shared__ float sP[4][8];
  __shared__ int   sC[4][8];
  float pacc[8]; int cacc[8];
  #pragma unroll
  for (int e = 0; e < 8; ++e) { pacc[e] = 0.f; cacc[e] = 0; }

  #pragma unroll 1
  for (int it = 0; it < 4; ++it) {
    int t = blockIdx.x * 16 + wv * 4 + it;
    const float4* xr = (const float4*)(x + (size_t)t * DIM);
    float acc[8];
    #pragma unroll
    for (int e = 0; e < 8; ++e) acc[e] = 0.f;
    #pragma unroll 1
    for (int i = 0; i < 8; ++i) {
      int j = i * 64 + lane;
      float4 v = xr[j];
      ushort4 o; o.x = f2bf(v.x); o.y = f2bf(v.y); o.z = f2bf(v.z); o.w = f2bf(v.w);
      *(ushort4*)(xb + (size_t)t * DIM + (size_t)j * 4) = o;
      const float* rr = rw + (size_t)j * 32;
      #pragma unroll
      for (int c = 0; c < 4; ++c) {
        float xv = (&v.x)[c];
        const float4* r4 = (const float4*)(rr + c * 8);
        float4 q0 = r4[0], q1 = r4[1];
        acc[0] += xv * q0.x; acc[1] += xv * q0.y; acc[2] += xv * q0.z; acc[3] += xv * q0.w;
        acc[4] += xv * q1.x; acc[5] += xv * q1.y; acc[6] += xv * q1.z; acc[7] += xv * q1.w;
      }
    }
    #pragma unroll
    for (int off = 32; off; off >>= 1) {
      #pragma unroll
      for (int e = 0; e < 8; ++e) acc[e] += __shfl_xor(acc[e], off);
    }
    float m = acc[0];
    #pragma unroll
    for (int e = 1; e < 8; ++e) m = fmaxf(m, acc[e]);
    float p[8], s = 0.f;
    #pragma unroll
    for (int e = 0; e < 8; ++e) { p[e] = __expf(acc[e] - m); s += p[e]; }
    float inv = 1.f / s;
    int i1 = 0; float p1 = p[0];
    #pragma unroll
    for (int e = 1; e < 8; ++e) if (p[e] > p1) { p1 = p[e]; i1 = e; }
    int i2 = -1; float p2 = -1.f;
    #pragma unroll
    for (int e = 0; e < 8; ++e) if (e != i1 && p[e] > p2) { p2 = p[e]; i2 = e; }
    float w1 = p1 / (p1 + p2);
    if (lane == 0) {
      topi[t] = i1 | (i2 << 8);
      topw[t] = w1;
      #pragma unroll
      for (int e = 0; e < 8; ++e) pacc[e] += p[e] * inv;
      cacc[i1]++; cacc[i2]++;
    }
  }
  if (lane == 0) {
    #pragma unroll
    for (int e = 0; e < 8; ++e) { sP[wv][e] = pacc[e]; sC[wv][e] = cacc[e]; }
  }
  __syncthreads();
  if (tid < 8) {
    float ps = sP[0][tid] + sP[1][tid] + sP[2][tid] + sP[3][tid];
    int   cs = sC[0][tid] + sC[1][tid] + sC[2][tid] + sC[3][tid];
    atomicAdd(&cnt[tid], cs);
    atomicAdd(&psum[tid], (unsigned long long)((double)ps * 1099511627776.0));
  }
}

// ---------------- scan + aux ----------------
__global__ void scan_aux_kernel(int* __restrict__ stats,
                                const unsigned long long* __restrict__ psum,
                                float* __restrict__ aux_out)
{
  if (threadIdx.x == 0 && blockIdx.x == 0) {
    int b = 0, tb = 0;
    for (int e = 0; e < 8; ++e) {
      stats[8 + e] = b; stats[16 + e] = b; stats[24 + e] = tb;
      tb += (stats[e] + 255) >> 8;
      b += stats[e];
    }
    stats[32] = tb;
    double s = 0.0;
    for (int e = 0; e < 8; ++e)
      s += (double)stats[e] * ((double)psum[e] * (1.0 / 1099511627776.0));
    aux_out[0] = (float)(4.0 * s / ((double)N_TOK * (double)N_TOK));
  }
}

// ---------------- placement ----------------
__global__ __launch_bounds__(256) void place_kernel(
    const int* __restrict__ topi, int* __restrict__ stats,
    int* __restrict__ lpk, int2* __restrict__ tpos)
{
  int t = blockIdx.x * 256 + threadIdx.x;
  if (t >= N_TOK) return;
  int pk = topi[t];
  int e1 = pk & 0xff, e2 = (pk >> 8) & 0xff;
  int p1 = atomicAdd(&stats[8 + e1], 1);
  lpk[p1] = t;
  int p2 = atomicAdd(&stats[8 + e2], 1);
  lpk[p2] = t;
  tpos[t] = make_int2(p1, p2);
}

// ---------------- gather bf16 tokens into 256-row chunk images ----------------
__global__ __launch_bounds__(256) void gather_x_kernel(
    const ushort* __restrict__ xb, const int* __restrict__ lpk,
    const int* __restrict__ stats, char* __restrict__ xgp)
{
  int b = blockIdx.x;
  if (b >= stats[32]) return;
  int e = 0;
  #pragma unroll
  for (int k = 1; k < 8; ++k) if (b >= stats[24 + k]) e = k;
  int tloc = b - stats[24 + e];
  int abase = stats[16 + e], Me = stats[e];

  int r = threadIdx.x;                          // row 0..255
  int lrow = tloc * 256 + r;
  bool valid = lrow < Me;
  const char* src = (const char*)xb + (valid ? (size_t)lpk[abase + lrow] * (DIM * 2) : 0);
  char* base = xgp + (size_t)b * (64 * 16384);
  int q = r >> 1;
  int p0 = (((r & 1) << 2) | 0) ^ (q & 7);
  int p1_ = (((r & 1) << 2) | 1) ^ (q & 7);
  int p2_ = (((r & 1) << 2) | 2) ^ (q & 7);
  int p3 = (((r & 1) << 2) | 3) ^ (q & 7);

  #pragma unroll 1
  for (int j = 0; j < 64; ++j) {
    uint4 v0, v1, v2, v3;
    if (valid) {
      v0 = *(const uint4*)(src + j * 64);
      v1 = *(const uint4*)(src + j * 64 + 16);
      v2 = *(const uint4*)(src + j * 64 + 32);
      v3 = *(const uint4*)(src + j * 64 + 48);
    } else {
      v0 = v1 = v2 = v3 = make_uint4(0, 0, 0, 0);
    }
    char* u = base + (size_t)j * 16384 + q * 128;
    *(uint4*)(u + p0 * 16) = v0;
    *(uint4*)(u + p1_ * 16) = v1;
    *(uint4*)(u + p2_ * 16) = v2;
    *(uint4*)(u + p3 * 16) = v3;
  }
}

// ---------------- pack wg+wu -> 256-row units (rows 0-127 gate, 128-255 up) ----------------
__global__ __launch_bounds__(256) void pack_gu_kernel(
    const float* __restrict__ wg, const float* __restrict__ wu, char* __restrict__ p1)
{
  int j = blockIdx.x, tn = blockIdx.y, e = blockIdx.z;
  __shared__ float tg[32][129];
  __shared__ float tu[32][129];
  int t = threadIdx.x;
  const float* gs = wg + ((size_t)e * DIM + j * 32) * FFN + tn * 128;
  const float* us = wu + ((size_t)e * DIM + j * 32) * FFN + tn * 128;
  #pragma unroll
  for (int k2 = 0; k2 < 4; ++k2) {
    int idx = t + k2 * 256;
    int kk = idx >> 5, fq = idx & 31;
    *(float4*)&tg[kk][fq * 4] = *(const float4*)(gs + (size_t)kk * FFN + fq * 4);
    *(float4*)&tu[kk][fq * 4] = *(const float4*)(us + (size_t)kk * FFN + fq * 4);
  }
  __syncthreads();
  char* dst = p1 + ((size_t)((e * 11 + tn) * 64 + j)) * 16384;
  #pragma unroll
  for (int k2 = 0; k2 < 4; ++k2) {
    int L = t + k2 * 256;
    int q = L >> 3, v = (L & 7) ^ (q & 7);
    int row = 2 * q + (v >> 2), s = v & 3;
    ushort u8[8];
    if (row < 128) {
      #pragma unroll
      for (int i = 0; i < 8; ++i) u8[i] = f2bf(tg[s * 8 + i][row]);
    } else {
      #pragma unroll
      for (int i = 0; i < 8; ++i) u8[i] = f2bf(tu[s * 8 + i][row - 128]);
    }
    *(ushort4*)(dst + (size_t)L * 16) = *(ushort4*)&u8[0];
    *(ushort4*)(dst + (size_t)L * 16 + 8) = *(ushort4*)&u8[4];
  }
}

// ---------------- pack wd -> 256-row units (rows = 256 d-cols) ----------------
__global__ __launch_bounds__(256) void pack_d_kernel(
    const float* __restrict__ wd, char* __restrict__ p2)
{
  int j = blockIdx.x, tn = blockIdx.y, e = blockIdx.z;
  __shared__ float t2[32][257];
  int t = threadIdx.x;
  const float* src = wd + ((size_t)e * FFN + j * 32) * DIM + tn * 256;
  #pragma unroll
  for (int k2 = 0; k2 < 8; ++k2) {
    int idx = t + k2 * 256;
    int kk = idx >> 6, dq = idx & 63;
    *(float4*)&t2[kk][dq * 4] = *(const float4*)(src + (size_t)kk * DIM + dq * 4);
  }
  __syncthreads();
  char* dst = p2 + ((size_t)((e * 8 + tn) * 44 + j)) * 16384;
  #pragma unroll
  for (int k2 = 0; k2 < 4; ++k2) {
    int L = t + k2 * 256;
    int q = L >> 3, v = (L & 7) ^ (q & 7);
    int row = 2 * q + (v >> 2), s = v & 3;
    ushort u8[8];
    #pragma unroll
    for (int i = 0; i < 8; ++i) u8[i] = f2bf(t2[s * 8 + i][row]);
    *(ushort4*)(dst + (size_t)L * 16) = *(ushort4*)&u8[0];
    *(ushort4*)(dst + (size_t)L * 16 + 8) = *(ushort4*)&u8[4];
  }
}

// =====================================================================
// GEMM core: 256x256 tile, BK=32, 8 waves (2M x 4N, 128x64 per wave),
// ring of 4 LDS slots (A 16KB + B 16KB each) = 128KB, 1 block/CU,
// prefetch distance 3, counted vmcnt(8)/4/0, 4-phase interleave per
// chunk, vmcnt -> s_barrier -> ds_read ordering (cross-wave safety).
// Slot reuse: iter j writes only slot (j+3)&3, whose readers all passed
// iter j-1's end barrier.
// =====================================================================

#define STG(PTR, J, OFS, LOFS) \
  gload16((PTR) + (size_t)(J) * 16384 + wv * 2048 + lane * 16 + (OFS), \
          sm + ((J) & 3) * 32768 + (LOFS) + wv * 2048 + (OFS))

#define KLOOP(NCH) \
  _Pragma("unroll") \
  for (int t_ = 0; t_ < 3; ++t_) { \
    STG(aP, t_, 0, 0); STG(aP, t_, 1024, 0); \
    STG(bP, t_, 0, 16384); STG(bP, t_, 1024, 16384); \
  } \
  _Pragma("unroll 1") \
  for (int j = 0; j < (NCH); ++j) { \
    if (j < (NCH) - 2)       asm volatile("s_waitcnt vmcnt(8)" ::: "memory"); \
    else if (j == (NCH) - 2) asm volatile("s_waitcnt vmcnt(4)" ::: "memory"); \
    else                     asm volatile("s_waitcnt vmcnt(0)" ::: "memory"); \
    BAR(); \
    int sb = (j & 3) * 32768; \
    bool pf = (j + 3 < (NCH)); \
    int4v va[8], vb[4]; \
    /* phase 1 */ \
    if (pf) STG(aP, j + 3, 0, 0); \
    _Pragma("unroll") for (int m = 0; m < 4; ++m) va[m] = dsread(sb + adA[m]); \
    vb[0] = dsread(sb + adB[0]); vb[1] = dsread(sb + adB[1]); \
    WAITL(); \
    __builtin_amdgcn_s_setprio(1); \
    _Pragma("unroll") for (int m = 0; m < 4; ++m) { \
      acc[m][0] = MFMA16(BC(va[m]), BC(vb[0]), acc[m][0]); \
      acc[m][1] = MFMA16(BC(va[m]), BC(vb[1]), acc[m][1]); } \
    __builtin_amdgcn_s_setprio(0); \
    /* phase 2 */ \
    if (pf) STG(aP, j + 3, 1024, 0); \
    vb[2] = dsread(sb + adB[2]); vb[3] = dsread(sb + adB[3]); \
    WAITL(); \
    __builtin_amdgcn_s_setprio(1); \
    _Pragma("unroll") for (int m = 0; m < 4; ++m) { \
      acc[m][2] = MFMA16(BC(va[m]), BC(vb[2]), acc[m][2]); \
      acc[m][3] = MFMA16(BC(va[m]), BC(vb[3]), acc[m][3]); } \
    __builtin_amdgcn_s_setprio(0); \
    /* phase 3 */ \
    if (pf) STG(bP, j + 3, 0, 16384); \
    _Pragma("unroll") for (int m = 0; m < 4; ++m) va[4 + m] = dsread(sb + adA[4 + m]); \
    WAITL(); \
    __builtin_amdgcn_s_setprio(1); \
    _Pragma("unroll") for (int m = 0; m < 4; ++m) { \
      acc[4 + m][0] = MFMA16(BC(va[4 + m]), BC(vb[0]), acc[4 + m][0]); \
      acc[4 + m][1] = MFMA16(BC(va[4 + m]), BC(vb[1]), acc[4 + m][1]); } \
    __builtin_amdgcn_s_setprio(0); \
    /* phase 4 */ \
    if (pf) STG(bP, j + 3, 1024, 16384); \
    __builtin_amdgcn_s_setprio(1); \
    _Pragma("unroll") for (int m = 0; m < 4; ++m) { \
      acc[4 + m][2] = MFMA16(BC(va[4 + m]), BC(vb[2]), acc[4 + m][2]); \
      acc[4 + m][3] = MFMA16(BC(va[4 + m]), BC(vb[3]), acc[4 + m][3]); } \
    __builtin_amdgcn_s_setprio(0); \
    BAR(); \
  }

// GEMM1: A = 256-token tile image, B = {gate,up} image (256 rows).
// grid 5632: e = bid&7 (XCD), Ll = bid>>3: tm = Ll/11, tn = Ll%11.
__global__ __launch_bounds__(512, 1) void gemm_gu_kernel(
    const char* __restrict__ xgp, const char* __restrict__ p1,
    const int* __restrict__ stats, char* __restrict__ hp)
{
  int bid = blockIdx.x;
  int e = bid & 7;
  int Ll = bid >> 3;
  int tm = Ll / 11, tn = Ll % 11;
  int Me = stats[e];
  if (tm * 256 >= Me) return;
  int tb = stats[24 + e];

  extern __shared__ char sm[];
  int tid = threadIdx.x, lane = tid & 63, wv = tid >> 6;
  const char* aP = xgp + (size_t)(tb + tm) * 64 * 16384;
  const char* bP = p1 + (size_t)((e * 11 + tn) * 64) * 16384;

  int wm = wv >> 2, wn = wv & 3, s = lane >> 4;
  int adA[8], adB[4];
  #pragma unroll
  for (int m = 0; m < 8; ++m) adA[m] = swz(wm * 128 + m * 16 + (lane & 15), s);
  #pragma unroll
  for (int n = 0; n < 4; ++n) adB[n] = 16384 + swz(wn * 64 + n * 16 + (lane & 15), s);

  f32x4 acc[8][4];
  #pragma unroll
  for (int m = 0; m < 8; ++m)
    #pragma unroll
    for (int n = 0; n < 4; ++n) acc[m][n] = (f32x4){0, 0, 0, 0};

  KLOOP(64);

  // ---- epilogue: waves wn>=2 hold up; exchange via LDS; wn<2 fuse SiLU ----
  __syncthreads();
  float* u_lds = (float*)sm;                  // [256][128] f32 = 128KB
  if (wn >= 2) {
    #pragma unroll
    for (int m = 0; m < 8; ++m)
      #pragma unroll
      for (int n = 0; n < 4; ++n)
        #pragma unroll
        for (int r = 0; r < 4; ++r) {
          int row = wm * 128 + m * 16 + (lane >> 4) * 4 + r;
          int fc = (wn - 2) * 64 + n * 16 + (lane & 15);
          u_lds[row * 128 + fc] = acc[m][n][r];
        }
  }
  __syncthreads();
  if (wn < 2) {
    char* hb = hp + (size_t)(tb + tm) * 44 * 16384;
    #pragma unroll
    for (int m = 0; m < 8; ++m)
      #pragma unroll
      for (int n = 0; n < 4; ++n)
        #pragma unroll
        for (int r = 0; r < 4; ++r) {
          int row = wm * 128 + m * 16 + (lane >> 4) * 4 + r;
          int fc = wn * 64 + n * 16 + (lane & 15);
          float g = acc[m][n][r];
          float u = u_lds[row * 128 + fc];
          float hv = g * u / (1.f + __expf(-g));
          int f = tn * 128 + fc;
          int j2 = f >> 5, s2 = (f >> 3) & 3, i2 = f & 7;
          int q = row >> 1;
          int p = (((row & 1) << 2) | s2) ^ (q & 7);
          *(ushort*)(hb + (size_t)j2 * 16384 + q * 128 + p * 16 + i2 * 2) = f2bf(hv);
        }
  }
}

// GEMM2: A = h image, B = down image; dense store to eo.
// grid 4096: e = bid&7, Ll = bid>>3: tm = Ll>>3, tn = Ll&7.
__global__ __launch_bounds__(512, 1) void gemm_down_kernel(
    const char* __restrict__ hp, const char* __restrict__ p2,
    const int* __restrict__ stats, float* __restrict__ eo)
{
  int bid = blockIdx.x;
  int e = bid & 7;
  int Ll = bid >> 3;
  int tm = Ll >> 3, tn = Ll & 7;
  int Me = stats[e];
  if (tm * 256 >= Me) return;
  int tb = stats[24 + e], abase = stats[16 + e];

  extern __shared__ char sm[];
  int tid = threadIdx.x, lane = tid & 63, wv = tid >> 6;
  const char* aP = hp + (size_t)(tb + tm) * 44 * 16384;
  const char* bP = p2 + (size_t)((e * 8 + tn) * 44) * 16384;

  int wm = wv >> 2, wn = wv & 3, s = lane >> 4;
  int adA[8], adB[4];
  #pragma unroll
  for (int m = 0; m < 8; ++m) adA[m] = swz(wm * 128 + m * 16 + (lane & 15), s);
  #pragma unroll
  for (int n = 0; n < 4; ++n) adB[n] = 16384 + swz(wn * 64 + n * 16 + (lane & 15), s);

  f32x4 acc[8][4];
  #pragma unroll
  for (int m = 0; m < 8; ++m)
    #pragma unroll
    for (int n = 0; n < 4; ++n) acc[m][n] = (f32x4){0, 0, 0, 0};

  KLOOP(44);

  int c0 = lane & 15, r0 = (lane >> 4) * 4;
  #pragma unroll
  for (int m = 0; m < 8; ++m) {
    #pragma unroll
    for (int r = 0; r < 4; ++r) {
      int lrow = tm * 256 + wm * 128 + m * 16 + r0 + r;
      if (lrow < Me) {
        float* dst = eo + (size_t)(abase + lrow) * DIM + tn * 256 + wn * 64 + c0;
        #pragma unroll
        for (int n = 0; n < 4; ++n) dst[n * 16] = acc[m][n][r];
      }
    }
  }
}

// ---------------- combine: out[t] = w1*eo[p1] + w2*eo[p2] ----------------
__global__ __launch_bounds__(256) void combine_kernel(
    const float* __restrict__ eo, const int2* __restrict__ tpos,
    const float* __restrict__ topw, float* __restrict__ out)
{
  int t = blockIdx.x;
  int2 tp = tpos[t];
  float w1 = topw[t], w2 = 1.f - w1;
  const float4* r1 = (const float4*)(eo + (size_t)tp.x * DIM);
  const float4* r2 = (const float4*)(eo + (size_t)tp.y * DIM);
  float4* o = (float4*)(out + (size_t)t * DIM);
  #pragma unroll
  for (int k = 0; k < 2; ++k) {
    int i = threadIdx.x + k * 256;
    float4 a = r1[i], b = r2[i];
    float4 c;
    c.x = w1 * a.x + w2 * b.x;
    c.y = w1 * a.y + w2 * b.y;
    c.z = w1 * a.z + w2 * b.z;
    c.w = w1 * a.w + w2 * b.w;
    o[i] = c;
  }
}

extern "C" void kernel_launch(void* const* d_in, const int* in_sizes, int n_in,
                              void* d_out, int out_size, void* d_ws, size_t ws_size,
                              hipStream_t stream)
{
  const float* x  = (const float*)d_in[0];
  const float* rw = (const float*)d_in[1];
  const float* wg = (const float*)d_in[2];
  const float* wu = (const float*)d_in[3];
  const float* wd = (const float*)d_in[4];
  float* out = (float*)d_out;

  char* ws = (char*)d_ws;
  char*   hp   = ws + HP_OFF;
  ushort* xb   = (ushort*)(ws + XB_OFF);
  char*   p1   = ws + P1_OFF;
  char*   p2   = ws + P2_OFF;
  float*  eo   = (float*)(ws + EO_OFF);
  char*   xgp  = ws + XGP_OFF;
  int*    lpk  = (int*)(ws + LPK_OFF);
  int*    topi = (int*)(ws + TI_OFF);
  float*  topw = (float*)(ws + TW_OFF);
  int2*   tpos = (int2*)(ws + TP_OFF);
  int*    stats = (int*)(ws + ST_OFF);
  unsigned long long* psum = (unsigned long long*)(ws + ST_OFF + 192);

  hipMemsetAsync(ws + ST_OFF, 0, 256, stream);

  router_kernel<<<512, 256, 0, stream>>>(x, rw, xb, topi, topw, stats, psum);
  scan_aux_kernel<<<1, 64, 0, stream>>>(stats, psum, out + (size_t)out_size - 1);
  place_kernel<<<32, 256, 0, stream>>>(topi, stats, lpk, tpos);

  gather_x_kernel<<<71, 256, 0, stream>>>(xb, lpk, stats, xgp);
  pack_gu_kernel<<<dim3(64, 11, 8), 256, 0, stream>>>(wg, wu, p1);

  gemm_gu_kernel<<<5632, 512, 131072, stream>>>(xgp, p1, stats, hp);

  pack_d_kernel<<<dim3(44, 8, 8), 256, 0, stream>>>(wd, p2);

  gemm_down_kernel<<<4096, 512, 131072, stream>>>(hp, p2, stats, eo);

  combine_kernel<<<8192, 256, 0, stream>>>(eo, tpos, topw, out);
}

// Round 10
// 534.484 us; speedup vs baseline: 1.2783x; 1.2783x over previous
//
#include <hip/hip_runtime.h>

#define N_TOK 8192
#define DIM   2048
#define FFN   1408

// ---------- ws layout (bytes); top = 258,932,992 ----------
// xb  [0, 33.5M)        prep(router) w -> gather r
// hp  [0, 49.0M)        gemm_gu w -> gemm_down r   (aliases dead xb)
// xgp [49.0M, 120.3M)   gather w -> gemm_gu r
// eo  [49.0M, 116.1M)   bf16, gemm_down w -> combine r (aliases dead xgp)
// p1  [120.3M, 212.6M)  prep(pack_gu) w -> gemm_gu r
// p2  [212.6M, 258.7M)  prep(pack_d) w -> gemm_down r
#define XB_OFF  0ull
#define HP_OFF  0ull
#define XGP_OFF 49020928ull
#define EO_OFF  49020928ull
#define P1_OFF  120324096ull
#define P2_OFF  212598784ull
#define LPK_OFF 258736128ull
#define TI_OFF  258801664ull
#define TW_OFF  258834432ull
#define TP_OFF  258867200ull
#define ST_OFF  258932736ull

typedef __bf16 bf16x8 __attribute__((ext_vector_type(8)));
typedef float  f32x4  __attribute__((ext_vector_type(4)));
typedef int    int4v  __attribute__((ext_vector_type(4)));
typedef __attribute__((address_space(1))) void as1_void;
typedef __attribute__((address_space(3))) void as3_void;

__device__ __forceinline__ void gload16(const void* g, void* l) {
  __builtin_amdgcn_global_load_lds((as1_void*)g, (as3_void*)l, 16, 0, 0);
}

__device__ __forceinline__ ushort f2bf(float f) {
  unsigned u = __builtin_bit_cast(unsigned, f);
  u += 0x7FFFu + ((u >> 16) & 1u);
  return (ushort)(u >> 16);
}
__device__ __forceinline__ float blo(unsigned w) { return __builtin_bit_cast(float, w << 16); }
__device__ __forceinline__ float bhi(unsigned w) { return __builtin_bit_cast(float, w & 0xffff0000u); }

__device__ __forceinline__ int4v dsread(int addr) {
  int4v d;
  asm volatile("ds_read_b128 %0, %1" : "=v"(d) : "v"(addr));
  return d;
}

#define WAITL() do { asm volatile("s_waitcnt lgkmcnt(0)" ::: "memory"); \
                     __builtin_amdgcn_sched_barrier(0); } while (0)
#define BAR()   __builtin_amdgcn_s_barrier()
#define MFMA16(a, b, c) __builtin_amdgcn_mfma_f32_16x16x32_bf16(a, b, c, 0, 0, 0)
#define BC(x) __builtin_bit_cast(bf16x8, x)

// 8KB unit = 128 rows x 32 k bf16. Piece (row, s): q=row>>1,
// p = (((row&1)<<2)|s) ^ (q&7); byte = q*128 + p*16.
__device__ __forceinline__ int swz(int row, int s) {
  int q = row >> 1;
  int p = (((row & 1) << 2) | s) ^ (q & 7);
  return q * 128 + p * 16;
}

// =====================================================================
// prep: fused router (+x->bf16) | pack_gu | pack_d.  All independent.
// blocks [0,512) router ; [512, 11776) pack_gu ; [11776, 17408) pack_d.
// =====================================================================
__global__ __launch_bounds__(256) void prep_kernel(
    const float* __restrict__ x, const float* __restrict__ rw,
    ushort* __restrict__ xb, int* __restrict__ topi, float* __restrict__ topw,
    int* __restrict__ cnt, unsigned long long* __restrict__ psum,
    const float* __restrict__ wg, const float* __restrict__ wu,
    const float* __restrict__ wd, char* __restrict__ p1, char* __restrict__ p2)
{
  __shared__ char smem[16640];
  int b = blockIdx.x;

  if (b < 512) {
    // ---------------- router ----------------
    int tid = threadIdx.x, lane = tid & 63, wv = tid >> 6;
    float (*sP)[8] = (float(*)[8])smem;
    int   (*sC)[8] = (int(*)[8])(smem + 128);
    float pacc[8]; int cacc[8];
    #pragma unroll
    for (int e = 0; e < 8; ++e) { pacc[e] = 0.f; cacc[e] = 0; }

    #pragma unroll 1
    for (int it = 0; it < 4; ++it) {
      int t = b * 16 + wv * 4 + it;
      const float4* xr = (const float4*)(x + (size_t)t * DIM);
      float acc[8];
      #pragma unroll
      for (int e = 0; e < 8; ++e) acc[e] = 0.f;
      #pragma unroll 1
      for (int i = 0; i < 8; ++i) {
        int j = i * 64 + lane;
        float4 v = xr[j];
        ushort4 o; o.x = f2bf(v.x); o.y = f2bf(v.y); o.z = f2bf(v.z); o.w = f2bf(v.w);
        *(ushort4*)(xb + (size_t)t * DIM + (size_t)j * 4) = o;
        const float* rr = rw + (size_t)j * 32;
        #pragma unroll
        for (int c = 0; c < 4; ++c) {
          float xv = (&v.x)[c];
          const float4* r4 = (const float4*)(rr + c * 8);
          float4 q0 = r4[0], q1 = r4[1];
          acc[0] += xv * q0.x; acc[1] += xv * q0.y; acc[2] += xv * q0.z; acc[3] += xv * q0.w;
          acc[4] += xv * q1.x; acc[5] += xv * q1.y; acc[6] += xv * q1.z; acc[7] += xv * q1.w;
        }
      }
      #pragma unroll
      for (int off = 32; off; off >>= 1) {
        #pragma unroll
        for (int e = 0; e < 8; ++e) acc[e] += __shfl_xor(acc[e], off);
      }
      float m = acc[0];
      #pragma unroll
      for (int e = 1; e < 8; ++e) m = fmaxf(m, acc[e]);
      float p[8], s = 0.f;
      #pragma unroll
      for (int e = 0; e < 8; ++e) { p[e] = __expf(acc[e] - m); s += p[e]; }
      float inv = 1.f / s;
      int i1 = 0; float p1v = p[0];
      #pragma unroll
      for (int e = 1; e < 8; ++e) if (p[e] > p1v) { p1v = p[e]; i1 = e; }
      int i2 = -1; float p2v = -1.f;
      #pragma unroll
      for (int e = 0; e < 8; ++e) if (e != i1 && p[e] > p2v) { p2v = p[e]; i2 = e; }
      float w1 = p1v / (p1v + p2v);
      if (lane == 0) {
        topi[t] = i1 | (i2 << 8);
        topw[t] = w1;
        #pragma unroll
        for (int e = 0; e < 8; ++e) pacc[e] += p[e] * inv;
        cacc[i1]++; cacc[i2]++;
      }
    }
    if (lane == 0) {
      #pragma unroll
      for (int e = 0; e < 8; ++e) { sP[wv][e] = pacc[e]; sC[wv][e] = cacc[e]; }
    }
    __syncthreads();
    if (tid < 8) {
      float ps = sP[0][tid] + sP[1][tid] + sP[2][tid] + sP[3][tid];
      int   cs = sC[0][tid] + sC[1][tid] + sC[2][tid] + sC[3][tid];
      atomicAdd(&cnt[tid], cs);
      atomicAdd(&psum[tid], (unsigned long long)((double)ps * 1099511627776.0));
    }
  } else if (b < 11776) {
    // ---------------- pack_gu: rows 0-63 gate, 64-127 up ----------------
    int q_ = b - 512;
    int j = q_ & 63, rest = q_ >> 6;
    int tn = rest % 22, e = rest / 22;
    float (*tg)[65] = (float(*)[65])smem;
    float (*tu)[65] = (float(*)[65])(smem + 8320);
    int t = threadIdx.x;
    const float* gs = wg + ((size_t)e * DIM + j * 32) * FFN + tn * 64;
    const float* us = wu + ((size_t)e * DIM + j * 32) * FFN + tn * 64;
    #pragma unroll
    for (int k2 = 0; k2 < 2; ++k2) {
      int idx = t + k2 * 256;
      int kk = idx >> 4, fq = idx & 15;
      *(float4*)&tg[kk][fq * 4] = *(const float4*)(gs + (size_t)kk * FFN + fq * 4);
      *(float4*)&tu[kk][fq * 4] = *(const float4*)(us + (size_t)kk * FFN + fq * 4);
    }
    __syncthreads();
    char* dst = p1 + ((size_t)((e * 22 + tn) * 64 + j)) * 8192;
    #pragma unroll
    for (int k2 = 0; k2 < 2; ++k2) {
      int L = t + k2 * 256;
      int q = L >> 3, v = (L & 7) ^ (q & 7);
      int r = 2 * q + (v >> 2), s = v & 3;
      const float* col = (r < 64) ? &tg[s * 8][r] : &tu[s * 8][r - 64];
      ushort u8[8];
      #pragma unroll
      for (int i = 0; i < 8; ++i) u8[i] = f2bf(col[i * 65]);
      *(ushort4*)(dst + (size_t)L * 16) = *(ushort4*)&u8[0];
      *(ushort4*)(dst + (size_t)L * 16 + 8) = *(ushort4*)&u8[4];
    }
  } else {
    // ---------------- pack_d: rows = 128 d-cols ----------------
    int q_ = b - 11776;
    int j = q_ % 44, rest = q_ / 44;
    int tn = rest & 15, e = rest >> 4;
    float (*t2)[129] = (float(*)[129])smem;
    int t = threadIdx.x;
    const float* src = wd + ((size_t)e * FFN + j * 32) * DIM + tn * 128;
    #pragma unroll
    for (int k2 = 0; k2 < 4; ++k2) {
      int idx = t + k2 * 256;
      int kk = idx >> 5, dq = idx & 31;
      *(float4*)&t2[kk][dq * 4] = *(const float4*)(src + (size_t)kk * DIM + dq * 4);
    }
    __syncthreads();
    char* dst = p2 + ((size_t)((e * 16 + tn) * 44 + j)) * 8192;
    #pragma unroll
    for (int k2 = 0; k2 < 2; ++k2) {
      int L = t + k2 * 256;
      int q = L >> 3, v = (L & 7) ^ (q & 7);
      int r = 2 * q + (v >> 2), s = v & 3;
      ushort u8[8];
      #pragma unroll
      for (int i = 0; i < 8; ++i) u8[i] = f2bf(t2[s * 8 + i][r]);
      *(ushort4*)(dst + (size_t)L * 16) = *(ushort4*)&u8[0];
      *(ushort4*)(dst + (size_t)L * 16 + 8) = *(ushort4*)&u8[4];
    }
  }
}

// ---------------- scan + aux ----------------
__global__ void scan_aux_kernel(int* __restrict__ stats,
                                const unsigned long long* __restrict__ psum,
                                float* __restrict__ aux_out)
{
  if (threadIdx.x == 0 && blockIdx.x == 0) {
    int b = 0, tb = 0;
    for (int e = 0; e < 8; ++e) {
      stats[8 + e] = b; stats[16 + e] = b; stats[24 + e] = tb;
      tb += (stats[e] + 127) >> 7;
      b += stats[e];
    }
    stats[32] = tb;
    double s = 0.0;
    for (int e = 0; e < 8; ++e)
      s += (double)stats[e] * ((double)psum[e] * (1.0 / 1099511627776.0));
    aux_out[0] = (float)(4.0 * s / ((double)N_TOK * (double)N_TOK));
  }
}

// ---------------- placement ----------------
__global__ __launch_bounds__(256) void place_kernel(
    const int* __restrict__ topi, int* __restrict__ stats,
    int* __restrict__ lpk, int2* __restrict__ tpos)
{
  int t = blockIdx.x * 256 + threadIdx.x;
  if (t >= N_TOK) return;
  int pk = topi[t];
  int e1 = pk & 0xff, e2 = (pk >> 8) & 0xff;
  int p1 = atomicAdd(&stats[8 + e1], 1);
  lpk[p1] = t;
  int p2 = atomicAdd(&stats[8 + e2], 1);
  lpk[p2] = t;
  tpos[t] = make_int2(p1, p2);
}

// ---------------- gather bf16 tokens into chunk-image layout ----------------
__global__ __launch_bounds__(256) void gather_x_kernel(
    const ushort* __restrict__ xb, const int* __restrict__ lpk,
    const int* __restrict__ stats, char* __restrict__ xgp)
{
  int b = blockIdx.x;
  int tile = b >> 1;
  if (tile >= stats[32]) return;
  int e = 0;
  #pragma unroll
  for (int k = 1; k < 8; ++k) if (tile >= stats[24 + k]) e = k;
  int tloc = tile - stats[24 + e];
  int abase = stats[16 + e], Me = stats[e];
  int half = b & 1;
  int lane = threadIdx.x & 63, wv = threadIdx.x >> 6;
  char* base = xgp + (size_t)tile * 64 * 8192;
  #pragma unroll 1
  for (int r = half * 64 + wv; r < half * 64 + 64; r += 4) {
    int lrow = tloc * 128 + r;
    bool valid = lrow < Me;
    const char* src = (const char*)xb + (valid ? (size_t)lpk[abase + lrow] * (DIM * 2) : 0);
    int q = r >> 1;
    #pragma unroll
    for (int it = 0; it < 4; ++it) {
      int c16 = it * 64 + lane;
      int j = c16 >> 2, s = c16 & 3;
      uint4 v;
      if (valid) v = *(const uint4*)(src + c16 * 16);
      else       v = make_uint4(0, 0, 0, 0);
      int p = (((r & 1) << 2) | s) ^ (q & 7);
      *(uint4*)(base + (size_t)j * 8192 + q * 128 + p * 16) = v;
    }
  }
}

// =====================================================================
// GEMM core: 128x128 tile, BK=32, 4 waves (2Mx2N), 32KB LDS dbuf,
// depth-1 prefetch, counted vmcnt(4), ~5 blocks/CU.
// XCD-locality: bid&7 -> XCD -> expert; within XCD: tm outer, tn fast.
// =====================================================================

#define GSTAGE(AC, BC_, BUF) do { int d_ = (BUF) * 16384 + wv * 2048; \
  gload16((AC) + wv * 2048 + lane * 16, sm + d_); \
  gload16((AC) + wv * 2048 + 1024 + lane * 16, sm + d_ + 1024); \
  gload16((BC_) + wv * 2048 + lane * 16, sm + d_ + 8192); \
  gload16((BC_) + wv * 2048 + 1024 + lane * 16, sm + d_ + 8192 + 1024); \
} while (0)

#define KLOOP(NCH) \
  GSTAGE(aP, bP, 0); \
  _Pragma("unroll 1") \
  for (int j = 0; j < (NCH); ++j) { \
    if (j + 1 < (NCH)) { \
      GSTAGE(aP + (size_t)(j + 1) * 8192, bP + (size_t)(j + 1) * 8192, (j + 1) & 1); \
      asm volatile("s_waitcnt vmcnt(4)" ::: "memory"); \
    } else { \
      asm volatile("s_waitcnt vmcnt(0)" ::: "memory"); \
    } \
    BAR(); \
    int sb = (j & 1) * 16384; \
    int4v va[4], vb[4]; \
    _Pragma("unroll") for (int n = 0; n < 4; ++n) vb[n] = dsread(sb + adB[n]); \
    _Pragma("unroll") for (int m = 0; m < 4; ++m) va[m] = dsread(sb + adA[m]); \
    WAITL(); \
    __builtin_amdgcn_s_setprio(1); \
    _Pragma("unroll") for (int m = 0; m < 4; ++m) \
      _Pragma("unroll") for (int n = 0; n < 4; ++n) \
        acc[m][n] = MFMA16(BC(va[m]), BC(vb[n]), acc[m][n]); \
    __builtin_amdgcn_s_setprio(0); \
    BAR(); \
  }

// GEMM1: A = token tile image, B = {gate,up} image; h written to gemm2 image.
__global__ __launch_bounds__(256, 4) void gemm_gu_kernel(
    const char* __restrict__ xgp, const char* __restrict__ p1,
    const int* __restrict__ stats, char* __restrict__ hp)
{
  int bid = blockIdx.x;
  int e = bid & 7;
  int Ll = bid >> 3;
  int tm = Ll / 22, tn = Ll % 22;
  int Me = stats[e];
  if (tm * 128 >= Me) return;
  int tb = stats[24 + e];

  __shared__ char sm[32768];
  int tid = threadIdx.x, lane = tid & 63, wv = tid >> 6;
  const char* aP = xgp + (size_t)(tb + tm) * 64 * 8192;
  const char* bP = p1 + (size_t)((e * 22 + tn) * 64) * 8192;

  int wm = wv >> 1, wn = wv & 1, s = lane >> 4;
  int adA[4], adB[4];
  #pragma unroll
  for (int m = 0; m < 4; ++m) adA[m] = swz(wm * 64 + m * 16 + (lane & 15), s);
  #pragma unroll
  for (int n = 0; n < 4; ++n) adB[n] = 8192 + swz(wn * 64 + n * 16 + (lane & 15), s);

  f32x4 acc[4][4];
  #pragma unroll
  for (int m = 0; m < 4; ++m)
    #pragma unroll
    for (int n = 0; n < 4; ++n) acc[m][n] = (f32x4){0, 0, 0, 0};

  KLOOP(64);

  // epilogue: wn==1 holds up-proj; exchange via LDS, wn==0 applies SiLU*u.
  float* u_lds = (float*)sm;          // [128][64] f32 = 32KB
  if (wn == 1) {
    #pragma unroll
    for (int m = 0; m < 4; ++m)
      #pragma unroll
      for (int n = 0; n < 4; ++n)
        #pragma unroll
        for (int r = 0; r < 4; ++r) {
          int row = wm * 64 + m * 16 + (lane >> 4) * 4 + r;
          int c = n * 16 + (lane & 15);
          u_lds[row * 64 + c] = acc[m][n][r];
        }
  }
  __syncthreads();
  if (wn == 0) {
    char* hb = hp + (size_t)(tb + tm) * 44 * 8192;
    #pragma unroll
    for (int m = 0; m < 4; ++m)
      #pragma unroll
      for (int n = 0; n < 4; ++n)
        #pragma unroll
        for (int r = 0; r < 4; ++r) {
          int row = wm * 64 + m * 16 + (lane >> 4) * 4 + r;
          int c = n * 16 + (lane & 15);
          float g = acc[m][n][r];
          float u = u_lds[row * 64 + c];
          float hv = g * u / (1.f + __expf(-g));
          int f = tn * 64 + c;
          int j2 = f >> 5, s2 = (f >> 3) & 3, i2 = f & 7;
          int q = row >> 1;
          int p = (((row & 1) << 2) | s2) ^ (q & 7);
          *(ushort*)(hb + (size_t)j2 * 8192 + q * 128 + p * 16 + i2 * 2) = f2bf(hv);
        }
  }
}

// GEMM2: A = h image, B = down image; dense bf16 store to eo (no atomics).
__global__ __launch_bounds__(256, 4) void gemm_down_kernel(
    const char* __restrict__ hp, const char* __restrict__ p2,
    const int* __restrict__ stats, ushort* __restrict__ eo)
{
  int bid = blockIdx.x;
  int e = bid & 7;
  int Ll = bid >> 3;
  int tm = Ll >> 4, tn = Ll & 15;
  int Me = stats[e];
  if (tm * 128 >= Me) return;
  int tb = stats[24 + e], abase = stats[16 + e];

  __shared__ char sm[32768];
  int tid = threadIdx.x, lane = tid & 63, wv = tid >> 6;
  const char* aP = hp + (size_t)(tb + tm) * 44 * 8192;
  const char* bP = p2 + (size_t)((e * 16 + tn) * 44) * 8192;

  int wm = wv >> 1, wn = wv & 1, s = lane >> 4;
  int adA[4], adB[4];
  #pragma unroll
  for (int m = 0; m < 4; ++m) adA[m] = swz(wm * 64 + m * 16 + (lane & 15), s);
  #pragma unroll
  for (int n = 0; n < 4; ++n) adB[n] = 8192 + swz(wn * 64 + n * 16 + (lane & 15), s);

  f32x4 acc[4][4];
  #pragma unroll
  for (int m = 0; m < 4; ++m)
    #pragma unroll
    for (int n = 0; n < 4; ++n) acc[m][n] = (f32x4){0, 0, 0, 0};

  KLOOP(44);

  int c0 = lane & 15, r0 = (lane >> 4) * 4;
  #pragma unroll
  for (int m = 0; m < 4; ++m) {
    #pragma unroll
    for (int r = 0; r < 4; ++r) {
      int lrow = tm * 128 + wm * 64 + m * 16 + r0 + r;
      if (lrow < Me) {
        ushort* dst = eo + (size_t)(abase + lrow) * DIM + tn * 128 + wn * 64 + c0;
        #pragma unroll
        for (int n = 0; n < 4; ++n) dst[n * 16] = f2bf(acc[m][n][r]);
      }
    }
  }
}

// ---------------- combine: out[t] = w1*eo[p1] + w2*eo[p2] (bf16 partials) ----------------
__global__ __launch_bounds__(256) void combine_kernel(
    const ushort* __restrict__ eo, const int2* __restrict__ tpos,
    const float* __restrict__ topw, float* __restrict__ out)
{
  int t = blockIdx.x;
  int2 tp = tpos[t];
  float w1 = topw[t], w2 = 1.f - w1;
  const uint4* r1 = (const uint4*)(eo + (size_t)tp.x * DIM);
  const uint4* r2 = (const uint4*)(eo + (size_t)tp.y * DIM);
  float4* o = (float4*)(out + (size_t)t * DIM);
  int i = threadIdx.x;
  uint4 a = r1[i], b = r2[i];
  float4 c0, c1;
  c0.x = w1 * blo(a.x) + w2 * blo(b.x);  c0.y = w1 * bhi(a.x) + w2 * bhi(b.x);
  c0.z = w1 * blo(a.y) + w2 * blo(b.y);  c0.w = w1 * bhi(a.y) + w2 * bhi(b.y);
  c1.x = w1 * blo(a.z) + w2 * blo(b.z);  c1.y = w1 * bhi(a.z) + w2 * bhi(b.z);
  c1.z = w1 * blo(a.w) + w2 * blo(b.w);  c1.w = w1 * bhi(a.w) + w2 * bhi(b.w);
  o[i * 2] = c0;
  o[i * 2 + 1] = c1;
}

extern "C" void kernel_launch(void* const* d_in, const int* in_sizes, int n_in,
                              void* d_out, int out_size, void* d_ws, size_t ws_size,
                              hipStream_t stream)
{
  const float* x  = (const float*)d_in[0];
  const float* rw = (const float*)d_in[1];
  const float* wg = (const float*)d_in[2];
  const float* wu = (const float*)d_in[3];
  const float* wd = (const float*)d_in[4];
  float* out = (float*)d_out;

  char* ws = (char*)d_ws;
  ushort* xb   = (ushort*)(ws + XB_OFF);
  char*   hp   = ws + HP_OFF;
  char*   xgp  = ws + XGP_OFF;
  ushort* eo   = (ushort*)(ws + EO_OFF);
  char*   p1   = ws + P1_OFF;
  char*   p2   = ws + P2_OFF;
  int*    lpk  = (int*)(ws + LPK_OFF);
  int*    topi = (int*)(ws + TI_OFF);
  float*  topw = (float*)(ws + TW_OFF);
  int2*   tpos = (int2*)(ws + TP_OFF);
  int*    stats = (int*)(ws + ST_OFF);
  unsigned long long* psum = (unsigned long long*)(ws + ST_OFF + 192);

  hipMemsetAsync(ws + ST_OFF, 0, 256, stream);

  prep_kernel<<<17408, 256, 0, stream>>>(x, rw, xb, topi, topw, stats, psum,
                                         wg, wu, wd, p1, p2);
  scan_aux_kernel<<<1, 64, 0, stream>>>(stats, psum, out + (size_t)out_size - 1);
  place_kernel<<<32, 256, 0, stream>>>(topi, stats, lpk, tpos);

  gather_x_kernel<<<272, 256, 0, stream>>>(xb, lpk, stats, xgp);

  gemm_gu_kernel<<<5632, 256, 0, stream>>>(xgp, p1, stats, hp);
  gemm_down_kernel<<<4096, 256, 0, stream>>>(hp, p2, stats, eo);

  combine_kernel<<<8192, 256, 0, stream>>>(eo, tpos, topw, out);
}

// Round 11
// 533.456 us; speedup vs baseline: 1.2808x; 1.0019x over previous
//
#include <hip/hip_runtime.h>

#define N_TOK 8192
#define DIM   2048
#define FFN   1408

// ---------- ws layout (bytes); top = 258,932,992 ----------
// xb  [0, 33.5M)        prep(router) w -> gather r
// hp  [0, 49.0M)        gemm_gu w -> gemm_down r   (aliases dead xb)
// xgp [49.0M, 120.3M)   gather w -> gemm_gu r
// eo  [49.0M, 116.1M)   bf16, gemm_down w -> combine r (aliases dead xgp)
// p1  [120.3M, 212.6M)  prep(pack_gu) w -> gemm_gu r
// p2  [212.6M, 258.7M)  prep(pack_d) w -> gemm_down r
#define XB_OFF  0ull
#define HP_OFF  0ull
#define XGP_OFF 49020928ull
#define EO_OFF  49020928ull
#define P1_OFF  120324096ull
#define P2_OFF  212598784ull
#define LPK_OFF 258736128ull
#define TI_OFF  258801664ull
#define TW_OFF  258834432ull
#define TP_OFF  258867200ull
#define ST_OFF  258932736ull

typedef __bf16 bf16x8 __attribute__((ext_vector_type(8)));
typedef float  f32x4  __attribute__((ext_vector_type(4)));
typedef int    int4v  __attribute__((ext_vector_type(4)));
typedef __attribute__((address_space(1))) void as1_void;
typedef __attribute__((address_space(3))) void as3_void;

__device__ __forceinline__ void gload16(const void* g, void* l) {
  __builtin_amdgcn_global_load_lds((as1_void*)g, (as3_void*)l, 16, 0, 0);
}

__device__ __forceinline__ ushort f2bf(float f) {
  unsigned u = __builtin_bit_cast(unsigned, f);
  u += 0x7FFFu + ((u >> 16) & 1u);
  return (ushort)(u >> 16);
}
__device__ __forceinline__ float blo(unsigned w) { return __builtin_bit_cast(float, w << 16); }
__device__ __forceinline__ float bhi(unsigned w) { return __builtin_bit_cast(float, w & 0xffff0000u); }

__device__ __forceinline__ int4v dsread(int addr) {
  int4v d;
  asm volatile("ds_read_b128 %0, %1" : "=v"(d) : "v"(addr));
  return d;
}

#define WAITL() do { asm volatile("s_waitcnt lgkmcnt(0)" ::: "memory"); \
                     __builtin_amdgcn_sched_barrier(0); } while (0)
#define BAR()   __builtin_amdgcn_s_barrier()
#define MFMA16(a, b, c) __builtin_amdgcn_mfma_f32_16x16x32_bf16(a, b, c, 0, 0, 0)
#define BC(x) __builtin_bit_cast(bf16x8, x)

// 8KB unit = 128 rows x 32 k bf16. Piece (row, s): q=row>>1,
// p = (((row&1)<<2)|s) ^ (q&7); byte = q*128 + p*16.
__device__ __forceinline__ int swz(int row, int s) {
  int q = row >> 1;
  int p = (((row & 1) << 2) | s) ^ (q & 7);
  return q * 128 + p * 16;
}

// =====================================================================
// prep: fused router (+x->bf16) | pack_gu | pack_d.  All independent.
// blocks [0,512) router ; [512, 11776) pack_gu ; [11776, 17408) pack_d.
// =====================================================================
__global__ __launch_bounds__(256) void prep_kernel(
    const float* __restrict__ x, const float* __restrict__ rw,
    ushort* __restrict__ xb, int* __restrict__ topi, float* __restrict__ topw,
    int* __restrict__ cnt, unsigned long long* __restrict__ psum,
    const float* __restrict__ wg, const float* __restrict__ wu,
    const float* __restrict__ wd, char* __restrict__ p1, char* __restrict__ p2)
{
  __shared__ char smem[16640];
  int b = blockIdx.x;

  if (b < 512) {
    // ---------------- router ----------------
    int tid = threadIdx.x, lane = tid & 63, wv = tid >> 6;
    float (*sP)[8] = (float(*)[8])smem;
    int   (*sC)[8] = (int(*)[8])(smem + 128);
    float pacc[8]; int cacc[8];
    #pragma unroll
    for (int e = 0; e < 8; ++e) { pacc[e] = 0.f; cacc[e] = 0; }

    #pragma unroll 1
    for (int it = 0; it < 4; ++it) {
      int t = b * 16 + wv * 4 + it;
      const float4* xr = (const float4*)(x + (size_t)t * DIM);
      float acc[8];
      #pragma unroll
      for (int e = 0; e < 8; ++e) acc[e] = 0.f;
      #pragma unroll 1
      for (int i = 0; i < 8; ++i) {
        int j = i * 64 + lane;
        float4 v = xr[j];
        ushort4 o; o.x = f2bf(v.x); o.y = f2bf(v.y); o.z = f2bf(v.z); o.w = f2bf(v.w);
        *(ushort4*)(xb + (size_t)t * DIM + (size_t)j * 4) = o;
        const float* rr = rw + (size_t)j * 32;
        #pragma unroll
        for (int c = 0; c < 4; ++c) {
          float xv = (&v.x)[c];
          const float4* r4 = (const float4*)(rr + c * 8);
          float4 q0 = r4[0], q1 = r4[1];
          acc[0] += xv * q0.x; acc[1] += xv * q0.y; acc[2] += xv * q0.z; acc[3] += xv * q0.w;
          acc[4] += xv * q1.x; acc[5] += xv * q1.y; acc[6] += xv * q1.z; acc[7] += xv * q1.w;
        }
      }
      #pragma unroll
      for (int off = 32; off; off >>= 1) {
        #pragma unroll
        for (int e = 0; e < 8; ++e) acc[e] += __shfl_xor(acc[e], off);
      }
      float m = acc[0];
      #pragma unroll
      for (int e = 1; e < 8; ++e) m = fmaxf(m, acc[e]);
      float p[8], s = 0.f;
      #pragma unroll
      for (int e = 0; e < 8; ++e) { p[e] = __expf(acc[e] - m); s += p[e]; }
      float inv = 1.f / s;
      int i1 = 0; float p1v = p[0];
      #pragma unroll
      for (int e = 1; e < 8; ++e) if (p[e] > p1v) { p1v = p[e]; i1 = e; }
      int i2 = -1; float p2v = -1.f;
      #pragma unroll
      for (int e = 0; e < 8; ++e) if (e != i1 && p[e] > p2v) { p2v = p[e]; i2 = e; }
      float w1 = p1v / (p1v + p2v);
      if (lane == 0) {
        topi[t] = i1 | (i2 << 8);
        topw[t] = w1;
        #pragma unroll
        for (int e = 0; e < 8; ++e) pacc[e] += p[e] * inv;
        cacc[i1]++; cacc[i2]++;
      }
    }
    if (lane == 0) {
      #pragma unroll
      for (int e = 0; e < 8; ++e) { sP[wv][e] = pacc[e]; sC[wv][e] = cacc[e]; }
    }
    __syncthreads();
    if (tid < 8) {
      float ps = sP[0][tid] + sP[1][tid] + sP[2][tid] + sP[3][tid];
      int   cs = sC[0][tid] + sC[1][tid] + sC[2][tid] + sC[3][tid];
      atomicAdd(&cnt[tid], cs);
      atomicAdd(&psum[tid], (unsigned long long)((double)ps * 1099511627776.0));
    }
  } else if (b < 11776) {
    // ---------------- pack_gu: rows 0-63 gate, 64-127 up ----------------
    int q_ = b - 512;
    int j = q_ & 63, rest = q_ >> 6;
    int tn = rest % 22, e = rest / 22;
    float (*tg)[65] = (float(*)[65])smem;
    float (*tu)[65] = (float(*)[65])(smem + 8320);
    int t = threadIdx.x;
    const float* gs = wg + ((size_t)e * DIM + j * 32) * FFN + tn * 64;
    const float* us = wu + ((size_t)e * DIM + j * 32) * FFN + tn * 64;
    #pragma unroll
    for (int k2 = 0; k2 < 2; ++k2) {
      int idx = t + k2 * 256;
      int kk = idx >> 4, fq = idx & 15;
      *(float4*)&tg[kk][fq * 4] = *(const float4*)(gs + (size_t)kk * FFN + fq * 4);
      *(float4*)&tu[kk][fq * 4] = *(const float4*)(us + (size_t)kk * FFN + fq * 4);
    }
    __syncthreads();
    char* dst = p1 + ((size_t)((e * 22 + tn) * 64 + j)) * 8192;
    #pragma unroll
    for (int k2 = 0; k2 < 2; ++k2) {
      int L = t + k2 * 256;
      int q = L >> 3, v = (L & 7) ^ (q & 7);
      int r = 2 * q + (v >> 2), s = v & 3;
      const float* col = (r < 64) ? &tg[s * 8][r] : &tu[s * 8][r - 64];
      ushort u8[8];
      #pragma unroll
      for (int i = 0; i < 8; ++i) u8[i] = f2bf(col[i * 65]);
      *(ushort4*)(dst + (size_t)L * 16) = *(ushort4*)&u8[0];
      *(ushort4*)(dst + (size_t)L * 16 + 8) = *(ushort4*)&u8[4];
    }
  } else {
    // ---------------- pack_d: rows = 128 d-cols ----------------
    int q_ = b - 11776;
    int j = q_ % 44, rest = q_ / 44;
    int tn = rest & 15, e = rest >> 4;
    float (*t2)[129] = (float(*)[129])smem;
    int t = threadIdx.x;
    const float* src = wd + ((size_t)e * FFN + j * 32) * DIM + tn * 128;
    #pragma unroll
    for (int k2 = 0; k2 < 4; ++k2) {
      int idx = t + k2 * 256;
      int kk = idx >> 5, dq = idx & 31;
      *(float4*)&t2[kk][dq * 4] = *(const float4*)(src + (size_t)kk * DIM + dq * 4);
    }
    __syncthreads();
    char* dst = p2 + ((size_t)((e * 16 + tn) * 44 + j)) * 8192;
    #pragma unroll
    for (int k2 = 0; k2 < 2; ++k2) {
      int L = t + k2 * 256;
      int q = L >> 3, v = (L & 7) ^ (q & 7);
      int r = 2 * q + (v >> 2), s = v & 3;
      ushort u8[8];
      #pragma unroll
      for (int i = 0; i < 8; ++i) u8[i] = f2bf(t2[s * 8 + i][r]);
      *(ushort4*)(dst + (size_t)L * 16) = *(ushort4*)&u8[0];
      *(ushort4*)(dst + (size_t)L * 16 + 8) = *(ushort4*)&u8[4];
    }
  }
}

// ---------------- scan + aux ----------------
__global__ void scan_aux_kernel(int* __restrict__ stats,
                                const unsigned long long* __restrict__ psum,
                                float* __restrict__ aux_out)
{
  if (threadIdx.x == 0 && blockIdx.x == 0) {
    int b = 0, tb = 0;
    for (int e = 0; e < 8; ++e) {
      stats[8 + e] = b; stats[16 + e] = b; stats[24 + e] = tb;
      tb += (stats[e] + 127) >> 7;
      b += stats[e];
    }
    stats[32] = tb;
    double s = 0.0;
    for (int e = 0; e < 8; ++e)
      s += (double)stats[e] * ((double)psum[e] * (1.0 / 1099511627776.0));
    aux_out[0] = (float)(4.0 * s / ((double)N_TOK * (double)N_TOK));
  }
}

// ---------------- placement ----------------
__global__ __launch_bounds__(256) void place_kernel(
    const int* __restrict__ topi, int* __restrict__ stats,
    int* __restrict__ lpk, int2* __restrict__ tpos)
{
  int t = blockIdx.x * 256 + threadIdx.x;
  if (t >= N_TOK) return;
  int pk = topi[t];
  int e1 = pk & 0xff, e2 = (pk >> 8) & 0xff;
  int p1 = atomicAdd(&stats[8 + e1], 1);
  lpk[p1] = t;
  int p2 = atomicAdd(&stats[8 + e2], 1);
  lpk[p2] = t;
  tpos[t] = make_int2(p1, p2);
}

// ---------------- gather bf16 tokens into chunk-image layout ----------------
__global__ __launch_bounds__(256) void gather_x_kernel(
    const ushort* __restrict__ xb, const int* __restrict__ lpk,
    const int* __restrict__ stats, char* __restrict__ xgp)
{
  int b = blockIdx.x;
  int tile = b >> 1;
  if (tile >= stats[32]) return;
  int e = 0;
  #pragma unroll
  for (int k = 1; k < 8; ++k) if (tile >= stats[24 + k]) e = k;
  int tloc = tile - stats[24 + e];
  int abase = stats[16 + e], Me = stats[e];
  int half = b & 1;
  int lane = threadIdx.x & 63, wv = threadIdx.x >> 6;
  char* base = xgp + (size_t)tile * 64 * 8192;
  #pragma unroll 1
  for (int r = half * 64 + wv; r < half * 64 + 64; r += 4) {
    int lrow = tloc * 128 + r;
    bool valid = lrow < Me;
    const char* src = (const char*)xb + (valid ? (size_t)lpk[abase + lrow] * (DIM * 2) : 0);
    int q = r >> 1;
    #pragma unroll
    for (int it = 0; it < 4; ++it) {
      int c16 = it * 64 + lane;
      int j = c16 >> 2, s = c16 & 3;
      uint4 v;
      if (valid) v = *(const uint4*)(src + c16 * 16);
      else       v = make_uint4(0, 0, 0, 0);
      int p = (((r & 1) << 2) | s) ^ (q & 7);
      *(uint4*)(base + (size_t)j * 8192 + q * 128 + p * 16) = v;
    }
  }
}

// =====================================================================
// GEMM core: 256x128 tile (A = 2 adjacent 128-row images, B = 1 image),
// BK=32, 4 waves of 64 rows x 128 B-rows each, 48KB LDS dbuf (24KB/slot),
// depth-1 prefetch, counted vmcnt(6), 2 blocks/CU, 87 FLOP/staged-byte
// (2.66x round-10 -> relieves the L2 staging bottleneck).
// XCD-locality: bid&7 -> XCD -> expert; within XCD: tm outer, tn fast.
// =====================================================================

#define GSTAGE(J, BUF) do { \
  size_t go_ = (size_t)(J) * 8192 + wv * 2048 + lane * 16; \
  int d_ = (BUF) * 24576 + wv * 2048; \
  gload16(aP0 + go_,        sm + d_); \
  gload16(aP0 + go_ + 1024, sm + d_ + 1024); \
  gload16(aP1 + go_,        sm + d_ + 8192); \
  gload16(aP1 + go_ + 1024, sm + d_ + 8192 + 1024); \
  gload16(bP + go_,         sm + d_ + 16384); \
  gload16(bP + go_ + 1024,  sm + d_ + 16384 + 1024); \
} while (0)

#define KLOOP(NCH) \
  GSTAGE(0, 0); \
  _Pragma("unroll 1") \
  for (int j = 0; j < (NCH); ++j) { \
    if (j + 1 < (NCH)) { \
      GSTAGE(j + 1, (j + 1) & 1); \
      asm volatile("s_waitcnt vmcnt(6)" ::: "memory"); \
    } else { \
      asm volatile("s_waitcnt vmcnt(0)" ::: "memory"); \
    } \
    BAR(); \
    int sb = (j & 1) * 24576; \
    int4v va[4], vb[8]; \
    _Pragma("unroll") for (int n = 0; n < 8; ++n) vb[n] = dsread(sb + adB[n]); \
    _Pragma("unroll") for (int m = 0; m < 4; ++m) va[m] = dsread(sb + adA[m]); \
    WAITL(); \
    __builtin_amdgcn_s_setprio(1); \
    _Pragma("unroll") for (int m = 0; m < 4; ++m) \
      _Pragma("unroll") for (int n = 0; n < 8; ++n) \
        acc[m][n] = MFMA16(BC(va[m]), BC(vb[n]), acc[m][n]); \
    __builtin_amdgcn_s_setprio(0); \
    BAR(); \
  }

// GEMM1: A = 256 tokens (2 images), B = {gate,up} image (rows 0-63 g, 64-127 u
// per 64 f-cols). Wave owns 64 tokens x all 128 B-rows -> SiLU in-register.
__global__ __launch_bounds__(256, 2) void gemm_gu_kernel(
    const char* __restrict__ xgp, const char* __restrict__ p1,
    const int* __restrict__ stats, char* __restrict__ hp)
{
  int bid = blockIdx.x;
  int e = bid & 7;
  int Ll = bid >> 3;
  int tm = Ll / 22, tn = Ll % 22;
  int Me = stats[e];
  if (tm * 256 >= Me) return;
  int tb = stats[24 + e];

  __shared__ char sm[49152];
  int tid = threadIdx.x, lane = tid & 63, wv = tid >> 6;
  const char* aP0 = xgp + (size_t)(tb + tm * 2) * 64 * 8192;
  const char* aP1 = aP0 + 64 * 8192;
  const char* bP = p1 + (size_t)((e * 22 + tn) * 64) * 8192;

  int s = lane >> 4;
  int adA[4], adB[8];
  #pragma unroll
  for (int m = 0; m < 4; ++m) {
    int row = wv * 64 + m * 16 + (lane & 15);
    adA[m] = (row >> 7) * 8192 + swz(row & 127, s);
  }
  #pragma unroll
  for (int n = 0; n < 8; ++n) adB[n] = 16384 + swz(n * 16 + (lane & 15), s);

  f32x4 acc[4][8];
  #pragma unroll
  for (int m = 0; m < 4; ++m)
    #pragma unroll
    for (int n = 0; n < 8; ++n) acc[m][n] = (f32x4){0, 0, 0, 0};

  KLOOP(64);

  // epilogue: gate = acc[m][n], up = acc[m][n+4] (same f-col) -> in-register SiLU.
  int r0 = (lane >> 4) * 4, cl = lane & 15;
  #pragma unroll
  for (int m = 0; m < 4; ++m) {
    #pragma unroll
    for (int r = 0; r < 4; ++r) {
      int row = wv * 64 + m * 16 + r0 + r;
      if (tm * 256 + row < Me) {
        char* hb = hp + (size_t)(tb + tm * 2 + (row >> 7)) * 44 * 8192;
        int lr = row & 127;
        int q = lr >> 1;
        #pragma unroll
        for (int n = 0; n < 4; ++n) {
          float g = acc[m][n][r];
          float u = acc[m][n + 4][r];
          float hv = g * u / (1.f + __expf(-g));
          int f = tn * 64 + n * 16 + cl;
          int j2 = f >> 5, s2 = (f >> 3) & 3, i2 = f & 7;
          int p = (((lr & 1) << 2) | s2) ^ (q & 7);
          *(ushort*)(hb + (size_t)j2 * 8192 + q * 128 + p * 16 + i2 * 2) = f2bf(hv);
        }
      }
    }
  }
}

// GEMM2: A = h (2 images), B = down image (128 d-cols); dense bf16 store to eo.
__global__ __launch_bounds__(256, 2) void gemm_down_kernel(
    const char* __restrict__ hp, const char* __restrict__ p2,
    const int* __restrict__ stats, ushort* __restrict__ eo)
{
  int bid = blockIdx.x;
  int e = bid & 7;
  int Ll = bid >> 3;
  int tm = Ll >> 4, tn = Ll & 15;
  int Me = stats[e];
  if (tm * 256 >= Me) return;
  int tb = stats[24 + e], abase = stats[16 + e];

  __shared__ char sm[49152];
  int tid = threadIdx.x, lane = tid & 63, wv = tid >> 6;
  const char* aP0 = hp + (size_t)(tb + tm * 2) * 44 * 8192;
  const char* aP1 = aP0 + 44 * 8192;
  const char* bP = p2 + (size_t)((e * 16 + tn) * 44) * 8192;

  int s = lane >> 4;
  int adA[4], adB[8];
  #pragma unroll
  for (int m = 0; m < 4; ++m) {
    int row = wv * 64 + m * 16 + (lane & 15);
    adA[m] = (row >> 7) * 8192 + swz(row & 127, s);
  }
  #pragma unroll
  for (int n = 0; n < 8; ++n) adB[n] = 16384 + swz(n * 16 + (lane & 15), s);

  f32x4 acc[4][8];
  #pragma unroll
  for (int m = 0; m < 4; ++m)
    #pragma unroll
    for (int n = 0; n < 8; ++n) acc[m][n] = (f32x4){0, 0, 0, 0};

  KLOOP(44);

  int c0 = lane & 15, r0 = (lane >> 4) * 4;
  #pragma unroll
  for (int m = 0; m < 4; ++m) {
    #pragma unroll
    for (int r = 0; r < 4; ++r) {
      int lrow = tm * 256 + wv * 64 + m * 16 + r0 + r;
      if (lrow < Me) {
        ushort* dst = eo + (size_t)(abase + lrow) * DIM + tn * 128 + c0;
        #pragma unroll
        for (int n = 0; n < 8; ++n) dst[n * 16] = f2bf(acc[m][n][r]);
      }
    }
  }
}

// ---------------- combine: out[t] = w1*eo[p1] + w2*eo[p2] (bf16 partials) ----------------
__global__ __launch_bounds__(256) void combine_kernel(
    const ushort* __restrict__ eo, const int2* __restrict__ tpos,
    const float* __restrict__ topw, float* __restrict__ out)
{
  int t = blockIdx.x;
  int2 tp = tpos[t];
  float w1 = topw[t], w2 = 1.f - w1;
  const uint4* r1 = (const uint4*)(eo + (size_t)tp.x * DIM);
  const uint4* r2 = (const uint4*)(eo + (size_t)tp.y * DIM);
  float4* o = (float4*)(out + (size_t)t * DIM);
  int i = threadIdx.x;
  uint4 a = r1[i], b = r2[i];
  float4 c0, c1;
  c0.x = w1 * blo(a.x) + w2 * blo(b.x);  c0.y = w1 * bhi(a.x) + w2 * bhi(b.x);
  c0.z = w1 * blo(a.y) + w2 * blo(b.y);  c0.w = w1 * bhi(a.y) + w2 * bhi(b.y);
  c1.x = w1 * blo(a.z) + w2 * blo(b.z);  c1.y = w1 * bhi(a.z) + w2 * bhi(b.z);
  c1.z = w1 * blo(a.w) + w2 * blo(b.w);  c1.w = w1 * bhi(a.w) + w2 * bhi(b.w);
  o[i * 2] = c0;
  o[i * 2 + 1] = c1;
}

extern "C" void kernel_launch(void* const* d_in, const int* in_sizes, int n_in,
                              void* d_out, int out_size, void* d_ws, size_t ws_size,
                              hipStream_t stream)
{
  const float* x  = (const float*)d_in[0];
  const float* rw = (const float*)d_in[1];
  const float* wg = (const float*)d_in[2];
  const float* wu = (const float*)d_in[3];
  const float* wd = (const float*)d_in[4];
  float* out = (float*)d_out;

  char* ws = (char*)d_ws;
  ushort* xb   = (ushort*)(ws + XB_OFF);
  char*   hp   = ws + HP_OFF;
  char*   xgp  = ws + XGP_OFF;
  ushort* eo   = (ushort*)(ws + EO_OFF);
  char*   p1   = ws + P1_OFF;
  char*   p2   = ws + P2_OFF;
  int*    lpk  = (int*)(ws + LPK_OFF);
  int*    topi = (int*)(ws + TI_OFF);
  float*  topw = (float*)(ws + TW_OFF);
  int2*   tpos = (int2*)(ws + TP_OFF);
  int*    stats = (int*)(ws + ST_OFF);
  unsigned long long* psum = (unsigned long long*)(ws + ST_OFF + 192);

  hipMemsetAsync(ws + ST_OFF, 0, 256, stream);

  prep_kernel<<<17408, 256, 0, stream>>>(x, rw, xb, topi, topw, stats, psum,
                                         wg, wu, wd, p1, p2);
  scan_aux_kernel<<<1, 64, 0, stream>>>(stats, psum, out + (size_t)out_size - 1);
  place_kernel<<<32, 256, 0, stream>>>(topi, stats, lpk, tpos);

  gather_x_kernel<<<272, 256, 0, stream>>>(xb, lpk, stats, xgp);

  gemm_gu_kernel<<<2816, 256, 0, stream>>>(xgp, p1, stats, hp);
  gemm_down_kernel<<<2048, 256, 0, stream>>>(hp, p2, stats, eo);

  combine_kernel<<<8192, 256, 0, stream>>>(eo, tpos, topw, out);
}

// Round 12
// 531.068 us; speedup vs baseline: 1.2866x; 1.0045x over previous
//
#include <hip/hip_runtime.h>

#define N_TOK 8192
#define DIM   2048
#define FFN   1408

// ---------- ws layout (bytes); top = 258,932,992 ----------
// xb  [0, 33.5M)        prep(router) w -> gather r
// hp  [0, 49.0M)        gemm_gu w -> gemm_down r   (aliases dead xb)
// xgp [49.0M, 120.3M)   gather w -> gemm_gu r
// eo  [49.0M, 116.1M)   bf16, gemm_down w -> combine r (aliases dead xgp)
// p1  [120.3M, 212.6M)  prep(pack_gu) w -> gemm_gu r
// p2  [212.6M, 258.7M)  prep(pack_d) w -> gemm_down r
#define XB_OFF  0ull
#define HP_OFF  0ull
#define XGP_OFF 49020928ull
#define EO_OFF  49020928ull
#define P1_OFF  120324096ull
#define P2_OFF  212598784ull
#define LPK_OFF 258736128ull
#define TI_OFF  258801664ull
#define TW_OFF  258834432ull
#define TP_OFF  258867200ull
#define ST_OFF  258932736ull

typedef __bf16 bf16x8 __attribute__((ext_vector_type(8)));
typedef float  f32x4  __attribute__((ext_vector_type(4)));
typedef int    int4v  __attribute__((ext_vector_type(4)));
typedef __attribute__((address_space(1))) void as1_void;
typedef __attribute__((address_space(3))) void as3_void;

__device__ __forceinline__ void gload16(const void* g, void* l) {
  __builtin_amdgcn_global_load_lds((as1_void*)g, (as3_void*)l, 16, 0, 0);
}

__device__ __forceinline__ ushort f2bf(float f) {
  unsigned u = __builtin_bit_cast(unsigned, f);
  u += 0x7FFFu + ((u >> 16) & 1u);
  return (ushort)(u >> 16);
}
__device__ __forceinline__ float blo(unsigned w) { return __builtin_bit_cast(float, w << 16); }
__device__ __forceinline__ float bhi(unsigned w) { return __builtin_bit_cast(float, w & 0xffff0000u); }

__device__ __forceinline__ int4v dsread(int addr) {
  int4v d;
  asm volatile("ds_read_b128 %0, %1" : "=v"(d) : "v"(addr));
  return d;
}

#define BAR()   __builtin_amdgcn_s_barrier()
#define MFMA16(a, b, c) __builtin_amdgcn_mfma_f32_16x16x32_bf16(a, b, c, 0, 0, 0)
#define BC(x) __builtin_bit_cast(bf16x8, x)

// 8KB unit = 128 rows x 32 k bf16. Piece (row, s): q=row>>1,
// p = (((row&1)<<2)|s) ^ (q&7); byte = q*128 + p*16.
__device__ __forceinline__ int swz(int row, int s) {
  int q = row >> 1;
  int p = (((row & 1) << 2) | s) ^ (q & 7);
  return q * 128 + p * 16;
}

// =====================================================================
// prep: fused router (+x->bf16) | pack_gu | pack_d.  All independent.
// blocks [0,512) router ; [512, 11776) pack_gu ; [11776, 17408) pack_d.
// =====================================================================
__global__ __launch_bounds__(256) void prep_kernel(
    const float* __restrict__ x, const float* __restrict__ rw,
    ushort* __restrict__ xb, int* __restrict__ topi, float* __restrict__ topw,
    int* __restrict__ cnt, unsigned long long* __restrict__ psum,
    const float* __restrict__ wg, const float* __restrict__ wu,
    const float* __restrict__ wd, char* __restrict__ p1, char* __restrict__ p2)
{
  __shared__ char smem[16640];
  int b = blockIdx.x;

  if (b < 512) {
    // ---------------- router ----------------
    int tid = threadIdx.x, lane = tid & 63, wv = tid >> 6;
    float (*sP)[8] = (float(*)[8])smem;
    int   (*sC)[8] = (int(*)[8])(smem + 128);
    float pacc[8]; int cacc[8];
    #pragma unroll
    for (int e = 0; e < 8; ++e) { pacc[e] = 0.f; cacc[e] = 0; }

    #pragma unroll 1
    for (int it = 0; it < 4; ++it) {
      int t = b * 16 + wv * 4 + it;
      const float4* xr = (const float4*)(x + (size_t)t * DIM);
      float acc[8];
      #pragma unroll
      for (int e = 0; e < 8; ++e) acc[e] = 0.f;
      #pragma unroll 1
      for (int i = 0; i < 8; ++i) {
        int j = i * 64 + lane;
        float4 v = xr[j];
        ushort4 o; o.x = f2bf(v.x); o.y = f2bf(v.y); o.z = f2bf(v.z); o.w = f2bf(v.w);
        *(ushort4*)(xb + (size_t)t * DIM + (size_t)j * 4) = o;
        const float* rr = rw + (size_t)j * 32;
        #pragma unroll
        for (int c = 0; c < 4; ++c) {
          float xv = (&v.x)[c];
          const float4* r4 = (const float4*)(rr + c * 8);
          float4 q0 = r4[0], q1 = r4[1];
          acc[0] += xv * q0.x; acc[1] += xv * q0.y; acc[2] += xv * q0.z; acc[3] += xv * q0.w;
          acc[4] += xv * q1.x; acc[5] += xv * q1.y; acc[6] += xv * q1.z; acc[7] += xv * q1.w;
        }
      }
      #pragma unroll
      for (int off = 32; off; off >>= 1) {
        #pragma unroll
        for (int e = 0; e < 8; ++e) acc[e] += __shfl_xor(acc[e], off);
      }
      float m = acc[0];
      #pragma unroll
      for (int e = 1; e < 8; ++e) m = fmaxf(m, acc[e]);
      float p[8], s = 0.f;
      #pragma unroll
      for (int e = 0; e < 8; ++e) { p[e] = __expf(acc[e] - m); s += p[e]; }
      float inv = 1.f / s;
      int i1 = 0; float p1v = p[0];
      #pragma unroll
      for (int e = 1; e < 8; ++e) if (p[e] > p1v) { p1v = p[e]; i1 = e; }
      int i2 = -1; float p2v = -1.f;
      #pragma unroll
      for (int e = 0; e < 8; ++e) if (e != i1 && p[e] > p2v) { p2v = p[e]; i2 = e; }
      float w1 = p1v / (p1v + p2v);
      if (lane == 0) {
        topi[t] = i1 | (i2 << 8);
        topw[t] = w1;
        #pragma unroll
        for (int e = 0; e < 8; ++e) pacc[e] += p[e] * inv;
        cacc[i1]++; cacc[i2]++;
      }
    }
    if (lane == 0) {
      #pragma unroll
      for (int e = 0; e < 8; ++e) { sP[wv][e] = pacc[e]; sC[wv][e] = cacc[e]; }
    }
    __syncthreads();
    if (tid < 8) {
      float ps = sP[0][tid] + sP[1][tid] + sP[2][tid] + sP[3][tid];
      int   cs = sC[0][tid] + sC[1][tid] + sC[2][tid] + sC[3][tid];
      atomicAdd(&cnt[tid], cs);
      atomicAdd(&psum[tid], (unsigned long long)((double)ps * 1099511627776.0));
    }
  } else if (b < 11776) {
    // ---------------- pack_gu: rows 0-63 gate, 64-127 up ----------------
    int q_ = b - 512;
    int j = q_ & 63, rest = q_ >> 6;
    int tn = rest % 22, e = rest / 22;
    float (*tg)[65] = (float(*)[65])smem;
    float (*tu)[65] = (float(*)[65])(smem + 8320);
    int t = threadIdx.x;
    const float* gs = wg + ((size_t)e * DIM + j * 32) * FFN + tn * 64;
    const float* us = wu + ((size_t)e * DIM + j * 32) * FFN + tn * 64;
    #pragma unroll
    for (int k2 = 0; k2 < 2; ++k2) {
      int idx = t + k2 * 256;
      int kk = idx >> 4, fq = idx & 15;
      *(float4*)&tg[kk][fq * 4] = *(const float4*)(gs + (size_t)kk * FFN + fq * 4);
      *(float4*)&tu[kk][fq * 4] = *(const float4*)(us + (size_t)kk * FFN + fq * 4);
    }
    __syncthreads();
    char* dst = p1 + ((size_t)((e * 22 + tn) * 64 + j)) * 8192;
    #pragma unroll
    for (int k2 = 0; k2 < 2; ++k2) {
      int L = t + k2 * 256;
      int q = L >> 3, v = (L & 7) ^ (q & 7);
      int r = 2 * q + (v >> 2), s = v & 3;
      const float* col = (r < 64) ? &tg[s * 8][r] : &tu[s * 8][r - 64];
      ushort u8[8];
      #pragma unroll
      for (int i = 0; i < 8; ++i) u8[i] = f2bf(col[i * 65]);
      *(ushort4*)(dst + (size_t)L * 16) = *(ushort4*)&u8[0];
      *(ushort4*)(dst + (size_t)L * 16 + 8) = *(ushort4*)&u8[4];
    }
  } else {
    // ---------------- pack_d: rows = 128 d-cols ----------------
    int q_ = b - 11776;
    int j = q_ % 44, rest = q_ / 44;
    int tn = rest & 15, e = rest >> 4;
    float (*t2)[129] = (float(*)[129])smem;
    int t = threadIdx.x;
    const float* src = wd + ((size_t)e * FFN + j * 32) * DIM + tn * 128;
    #pragma unroll
    for (int k2 = 0; k2 < 4; ++k2) {
      int idx = t + k2 * 256;
      int kk = idx >> 5, dq = idx & 31;
      *(float4*)&t2[kk][dq * 4] = *(const float4*)(src + (size_t)kk * DIM + dq * 4);
    }
    __syncthreads();
    char* dst = p2 + ((size_t)((e * 16 + tn) * 44 + j)) * 8192;
    #pragma unroll
    for (int k2 = 0; k2 < 2; ++k2) {
      int L = t + k2 * 256;
      int q = L >> 3, v = (L & 7) ^ (q & 7);
      int r = 2 * q + (v >> 2), s = v & 3;
      ushort u8[8];
      #pragma unroll
      for (int i = 0; i < 8; ++i) u8[i] = f2bf(t2[s * 8 + i][r]);
      *(ushort4*)(dst + (size_t)L * 16) = *(ushort4*)&u8[0];
      *(ushort4*)(dst + (size_t)L * 16 + 8) = *(ushort4*)&u8[4];
    }
  }
}

// ---------------- scan + aux ----------------
__global__ void scan_aux_kernel(int* __restrict__ stats,
                                const unsigned long long* __restrict__ psum,
                                float* __restrict__ aux_out)
{
  if (threadIdx.x == 0 && blockIdx.x == 0) {
    int b = 0, tb = 0;
    for (int e = 0; e < 8; ++e) {
      stats[8 + e] = b; stats[16 + e] = b; stats[24 + e] = tb;
      tb += (stats[e] + 127) >> 7;
      b += stats[e];
    }
    stats[32] = tb;
    double s = 0.0;
    for (int e = 0; e < 8; ++e)
      s += (double)stats[e] * ((double)psum[e] * (1.0 / 1099511627776.0));
    aux_out[0] = (float)(4.0 * s / ((double)N_TOK * (double)N_TOK));
  }
}

// ---------------- placement ----------------
__global__ __launch_bounds__(256) void place_kernel(
    const int* __restrict__ topi, int* __restrict__ stats,
    int* __restrict__ lpk, int2* __restrict__ tpos)
{
  int t = blockIdx.x * 256 + threadIdx.x;
  if (t >= N_TOK) return;
  int pk = topi[t];
  int e1 = pk & 0xff, e2 = (pk >> 8) & 0xff;
  int p1 = atomicAdd(&stats[8 + e1], 1);
  lpk[p1] = t;
  int p2 = atomicAdd(&stats[8 + e2], 1);
  lpk[p2] = t;
  tpos[t] = make_int2(p1, p2);
}

// ---------------- gather bf16 tokens into chunk-image layout ----------------
__global__ __launch_bounds__(256) void gather_x_kernel(
    const ushort* __restrict__ xb, const int* __restrict__ lpk,
    const int* __restrict__ stats, char* __restrict__ xgp)
{
  int b = blockIdx.x;
  int tile = b >> 1;
  if (tile >= stats[32]) return;
  int e = 0;
  #pragma unroll
  for (int k = 1; k < 8; ++k) if (tile >= stats[24 + k]) e = k;
  int tloc = tile - stats[24 + e];
  int abase = stats[16 + e], Me = stats[e];
  int half = b & 1;
  int lane = threadIdx.x & 63, wv = threadIdx.x >> 6;
  char* base = xgp + (size_t)tile * 64 * 8192;
  #pragma unroll 1
  for (int r = half * 64 + wv; r < half * 64 + 64; r += 4) {
    int lrow = tloc * 128 + r;
    bool valid = lrow < Me;
    const char* src = (const char*)xb + (valid ? (size_t)lpk[abase + lrow] * (DIM * 2) : 0);
    int q = r >> 1;
    #pragma unroll
    for (int it = 0; it < 4; ++it) {
      int c16 = it * 64 + lane;
      int j = c16 >> 2, s = c16 & 3;
      uint4 v;
      if (valid) v = *(const uint4*)(src + c16 * 16);
      else       v = make_uint4(0, 0, 0, 0);
      int p = (((r & 1) << 2) | s) ^ (q & 7);
      *(uint4*)(base + (size_t)j * 8192 + q * 128 + p * 16) = v;
    }
  }
}

// =====================================================================
// GEMM core: 256x128 tile (A = 2 adjacent 128-row images, B = 1 image),
// BK=32, 4 waves of 64 rows x 128 B-rows each, 48KB LDS dbuf (24KB/slot),
// depth-1 prefetch, counted vmcnt(6), 2 blocks/CU.
// NEW: counted lgkmcnt split (4 then 0) so the last 4 ds_reads' latency
// hides under the first 16 MFMAs (was: lgkmcnt(0) serializing all 12
// reads before any MFMA -> ~50% stall).
// XCD-locality: bid&7 -> XCD -> expert; within XCD: tm outer, tn fast.
// =====================================================================

#define GSTAGE(J, BUF) do { \
  size_t go_ = (size_t)(J) * 8192 + wv * 2048 + lane * 16; \
  int d_ = (BUF) * 24576 + wv * 2048; \
  gload16(aP0 + go_,        sm + d_); \
  gload16(aP0 + go_ + 1024, sm + d_ + 1024); \
  gload16(aP1 + go_,        sm + d_ + 8192); \
  gload16(aP1 + go_ + 1024, sm + d_ + 8192 + 1024); \
  gload16(bP + go_,         sm + d_ + 16384); \
  gload16(bP + go_ + 1024,  sm + d_ + 16384 + 1024); \
} while (0)

#define KLOOP(NCH) \
  GSTAGE(0, 0); \
  _Pragma("unroll 1") \
  for (int j = 0; j < (NCH); ++j) { \
    if (j + 1 < (NCH)) { \
      GSTAGE(j + 1, (j + 1) & 1); \
      asm volatile("s_waitcnt vmcnt(6)" ::: "memory"); \
    } else { \
      asm volatile("s_waitcnt vmcnt(0)" ::: "memory"); \
    } \
    BAR(); \
    int sb = (j & 1) * 24576; \
    int4v va[4], vb[8]; \
    _Pragma("unroll") for (int n = 0; n < 4; ++n) vb[n] = dsread(sb + adB[n]); \
    _Pragma("unroll") for (int m = 0; m < 4; ++m) va[m] = dsread(sb + adA[m]); \
    _Pragma("unroll") for (int n = 4; n < 8; ++n) vb[n] = dsread(sb + adB[n]); \
    asm volatile("s_waitcnt lgkmcnt(4)" ::: "memory"); \
    __builtin_amdgcn_sched_barrier(0); \
    __builtin_amdgcn_s_setprio(1); \
    _Pragma("unroll") for (int m = 0; m < 4; ++m) \
      _Pragma("unroll") for (int n = 0; n < 4; ++n) \
        acc[m][n] = MFMA16(BC(va[m]), BC(vb[n]), acc[m][n]); \
    __builtin_amdgcn_s_setprio(0); \
    asm volatile("s_waitcnt lgkmcnt(0)" ::: "memory"); \
    __builtin_amdgcn_sched_barrier(0); \
    __builtin_amdgcn_s_setprio(1); \
    _Pragma("unroll") for (int m = 0; m < 4; ++m) \
      _Pragma("unroll") for (int n = 4; n < 8; ++n) \
        acc[m][n] = MFMA16(BC(va[m]), BC(vb[n]), acc[m][n]); \
    __builtin_amdgcn_s_setprio(0); \
    BAR(); \
  }

// GEMM1: A = 256 tokens (2 images), B = {gate,up} image (rows 0-63 g, 64-127 u
// per 64 f-cols). Wave owns 64 tokens x all 128 B-rows -> SiLU in-register.
__global__ __launch_bounds__(256, 2) void gemm_gu_kernel(
    const char* __restrict__ xgp, const char* __restrict__ p1,
    const int* __restrict__ stats, char* __restrict__ hp)
{
  int bid = blockIdx.x;
  int e = bid & 7;
  int Ll = bid >> 3;
  int tm = Ll / 22, tn = Ll % 22;
  int Me = stats[e];
  if (tm * 256 >= Me) return;
  int tb = stats[24 + e];

  __shared__ char sm[49152];
  int tid = threadIdx.x, lane = tid & 63, wv = tid >> 6;
  const char* aP0 = xgp + (size_t)(tb + tm * 2) * 64 * 8192;
  const char* aP1 = aP0 + 64 * 8192;
  const char* bP = p1 + (size_t)((e * 22 + tn) * 64) * 8192;

  int s = lane >> 4;
  int adA[4], adB[8];
  #pragma unroll
  for (int m = 0; m < 4; ++m) {
    int row = wv * 64 + m * 16 + (lane & 15);
    adA[m] = (row >> 7) * 8192 + swz(row & 127, s);
  }
  #pragma unroll
  for (int n = 0; n < 8; ++n) adB[n] = 16384 + swz(n * 16 + (lane & 15), s);

  f32x4 acc[4][8];
  #pragma unroll
  for (int m = 0; m < 4; ++m)
    #pragma unroll
    for (int n = 0; n < 8; ++n) acc[m][n] = (f32x4){0, 0, 0, 0};

  KLOOP(64);

  // epilogue: gate = acc[m][n], up = acc[m][n+4] (same f-col) -> in-register SiLU.
  int r0 = (lane >> 4) * 4, cl = lane & 15;
  #pragma unroll
  for (int m = 0; m < 4; ++m) {
    #pragma unroll
    for (int r = 0; r < 4; ++r) {
      int row = wv * 64 + m * 16 + r0 + r;
      if (tm * 256 + row < Me) {
        char* hb = hp + (size_t)(tb + tm * 2 + (row >> 7)) * 44 * 8192;
        int lr = row & 127;
        int q = lr >> 1;
        #pragma unroll
        for (int n = 0; n < 4; ++n) {
          float g = acc[m][n][r];
          float u = acc[m][n + 4][r];
          float hv = g * u / (1.f + __expf(-g));
          int f = tn * 64 + n * 16 + cl;
          int j2 = f >> 5, s2 = (f >> 3) & 3, i2 = f & 7;
          int p = (((lr & 1) << 2) | s2) ^ (q & 7);
          *(ushort*)(hb + (size_t)j2 * 8192 + q * 128 + p * 16 + i2 * 2) = f2bf(hv);
        }
      }
    }
  }
}

// GEMM2: A = h (2 images), B = down image (128 d-cols); dense bf16 store to eo.
__global__ __launch_bounds__(256, 2) void gemm_down_kernel(
    const char* __restrict__ hp, const char* __restrict__ p2,
    const int* __restrict__ stats, ushort* __restrict__ eo)
{
  int bid = blockIdx.x;
  int e = bid & 7;
  int Ll = bid >> 3;
  int tm = Ll >> 4, tn = Ll & 15;
  int Me = stats[e];
  if (tm * 256 >= Me) return;
  int tb = stats[24 + e], abase = stats[16 + e];

  __shared__ char sm[49152];
  int tid = threadIdx.x, lane = tid & 63, wv = tid >> 6;
  const char* aP0 = hp + (size_t)(tb + tm * 2) * 44 * 8192;
  const char* aP1 = aP0 + 44 * 8192;
  const char* bP = p2 + (size_t)((e * 16 + tn) * 44) * 8192;

  int s = lane >> 4;
  int adA[4], adB[8];
  #pragma unroll
  for (int m = 0; m < 4; ++m) {
    int row = wv * 64 + m * 16 + (lane & 15);
    adA[m] = (row >> 7) * 8192 + swz(row & 127, s);
  }
  #pragma unroll
  for (int n = 0; n < 8; ++n) adB[n] = 16384 + swz(n * 16 + (lane & 15), s);

  f32x4 acc[4][8];
  #pragma unroll
  for (int m = 0; m < 4; ++m)
    #pragma unroll
    for (int n = 0; n < 8; ++n) acc[m][n] = (f32x4){0, 0, 0, 0};

  KLOOP(44);

  int c0 = lane & 15, r0 = (lane >> 4) * 4;
  #pragma unroll
  for (int m = 0; m < 4; ++m) {
    #pragma unroll
    for (int r = 0; r < 4; ++r) {
      int lrow = tm * 256 + wv * 64 + m * 16 + r0 + r;
      if (lrow < Me) {
        ushort* dst = eo + (size_t)(abase + lrow) * DIM + tn * 128 + c0;
        #pragma unroll
        for (int n = 0; n < 8; ++n) dst[n * 16] = f2bf(acc[m][n][r]);
      }
    }
  }
}

// ---------------- combine: out[t] = w1*eo[p1] + w2*eo[p2] (bf16 partials) ----------------
__global__ __launch_bounds__(256) void combine_kernel(
    const ushort* __restrict__ eo, const int2* __restrict__ tpos,
    const float* __restrict__ topw, float* __restrict__ out)
{
  int t = blockIdx.x;
  int2 tp = tpos[t];
  float w1 = topw[t], w2 = 1.f - w1;
  const uint4* r1 = (const uint4*)(eo + (size_t)tp.x * DIM);
  const uint4* r2 = (const uint4*)(eo + (size_t)tp.y * DIM);
  float4* o = (float4*)(out + (size_t)t * DIM);
  int i = threadIdx.x;
  uint4 a = r1[i], b = r2[i];
  float4 c0, c1;
  c0.x = w1 * blo(a.x) + w2 * blo(b.x);  c0.y = w1 * bhi(a.x) + w2 * bhi(b.x);
  c0.z = w1 * blo(a.y) + w2 * blo(b.y);  c0.w = w1 * bhi(a.y) + w2 * bhi(b.y);
  c1.x = w1 * blo(a.z) + w2 * blo(b.z);  c1.y = w1 * bhi(a.z) + w2 * bhi(b.z);
  c1.z = w1 * blo(a.w) + w2 * blo(b.w);  c1.w = w1 * bhi(a.w) + w2 * bhi(b.w);
  o[i * 2] = c0;
  o[i * 2 + 1] = c1;
}

extern "C" void kernel_launch(void* const* d_in, const int* in_sizes, int n_in,
                              void* d_out, int out_size, void* d_ws, size_t ws_size,
                              hipStream_t stream)
{
  const float* x  = (const float*)d_in[0];
  const float* rw = (const float*)d_in[1];
  const float* wg = (const float*)d_in[2];
  const float* wu = (const float*)d_in[3];
  const float* wd = (const float*)d_in[4];
  float* out = (float*)d_out;

  char* ws = (char*)d_ws;
  ushort* xb   = (ushort*)(ws + XB_OFF);
  char*   hp   = ws + HP_OFF;
  char*   xgp  = ws + XGP_OFF;
  ushort* eo   = (ushort*)(ws + EO_OFF);
  char*   p1   = ws + P1_OFF;
  char*   p2   = ws + P2_OFF;
  int*    lpk  = (int*)(ws + LPK_OFF);
  int*    topi = (int*)(ws + TI_OFF);
  float*  topw = (float*)(ws + TW_OFF);
  int2*   tpos = (int2*)(ws + TP_OFF);
  int*    stats = (int*)(ws + ST_OFF);
  unsigned long long* psum = (unsigned long long*)(ws + ST_OFF + 192);

  hipMemsetAsync(ws + ST_OFF, 0, 256, stream);

  prep_kernel<<<17408, 256, 0, stream>>>(x, rw, xb, topi, topw, stats, psum,
                                         wg, wu, wd, p1, p2);
  scan_aux_kernel<<<1, 64, 0, stream>>>(stats, psum, out + (size_t)out_size - 1);
  place_kernel<<<32, 256, 0, stream>>>(topi, stats, lpk, tpos);

  gather_x_kernel<<<272, 256, 0, stream>>>(xb, lpk, stats, xgp);

  gemm_gu_kernel<<<2816, 256, 0, stream>>>(xgp, p1, stats, hp);
  gemm_down_kernel<<<2048, 256, 0, stream>>>(hp, p2, stats, eo);

  combine_kernel<<<8192, 256, 0, stream>>>(eo, tpos, topw, out);
}

// Round 13
// 517.244 us; speedup vs baseline: 1.3209x; 1.0267x over previous
//
#include <hip/hip_runtime.h>

#define N_TOK 8192
#define DIM   2048
#define FFN   1408

// ---------- ws layout (bytes); top = 258,932,992 ----------
// xb  [0, 33.5M)        prep(router) w -> gather r
// hp  [0, 49.0M)        gemm_gu w -> gemm_down r   (aliases dead xb)
// xgp [49.0M, 120.3M)   gather w -> gemm_gu r
// eo  [49.0M, 116.1M)   bf16, gemm_down w -> combine r (aliases dead xgp)
// p1  [120.3M, 212.6M)  prep(pack_gu) w -> gemm_gu r
// p2  [212.6M, 258.7M)  prep(pack_d) w -> gemm_down r
#define XB_OFF  0ull
#define HP_OFF  0ull
#define XGP_OFF 49020928ull
#define EO_OFF  49020928ull
#define P1_OFF  120324096ull
#define P2_OFF  212598784ull
#define LPK_OFF 258736128ull
#define TI_OFF  258801664ull
#define TW_OFF  258834432ull
#define TP_OFF  258867200ull
#define ST_OFF  258932736ull

typedef __bf16 bf16x8 __attribute__((ext_vector_type(8)));
typedef float  f32x4  __attribute__((ext_vector_type(4)));
typedef int    int4v  __attribute__((ext_vector_type(4)));
typedef __attribute__((address_space(1))) void as1_void;
typedef __attribute__((address_space(3))) void as3_void;

__device__ __forceinline__ void gload16(const void* g, void* l) {
  __builtin_amdgcn_global_load_lds((as1_void*)g, (as3_void*)l, 16, 0, 0);
}

__device__ __forceinline__ ushort f2bf(float f) {
  unsigned u = __builtin_bit_cast(unsigned, f);
  u += 0x7FFFu + ((u >> 16) & 1u);
  return (ushort)(u >> 16);
}
__device__ __forceinline__ float blo(unsigned w) { return __builtin_bit_cast(float, w << 16); }
__device__ __forceinline__ float bhi(unsigned w) { return __builtin_bit_cast(float, w & 0xffff0000u); }

__device__ __forceinline__ int4v dsread(int addr) {
  int4v d;
  asm volatile("ds_read_b128 %0, %1" : "=v"(d) : "v"(addr));
  return d;
}

#define BAR()   __builtin_amdgcn_s_barrier()
#define MFMA16(a, b, c) __builtin_amdgcn_mfma_f32_16x16x32_bf16(a, b, c, 0, 0, 0)
#define BC(x) __builtin_bit_cast(bf16x8, x)

// 8KB unit = 128 rows x 32 k bf16. Piece (row, s): q=row>>1,
// p = (((row&1)<<2)|s) ^ (q&7); byte = q*128 + p*16.
__device__ __forceinline__ int swz(int row, int s) {
  int q = row >> 1;
  int p = (((row & 1) << 2) | s) ^ (q & 7);
  return q * 128 + p * 16;
}

// =====================================================================
// prep: fused router (+x->bf16) | pack_gu | pack_d.  All independent.
// blocks [0,512) router ; [512, 11776) pack_gu ; [11776, 17408) pack_d.
// =====================================================================
__global__ __launch_bounds__(256) void prep_kernel(
    const float* __restrict__ x, const float* __restrict__ rw,
    ushort* __restrict__ xb, int* __restrict__ topi, float* __restrict__ topw,
    int* __restrict__ cnt, unsigned long long* __restrict__ psum,
    const float* __restrict__ wg, const float* __restrict__ wu,
    const float* __restrict__ wd, char* __restrict__ p1, char* __restrict__ p2)
{
  __shared__ char smem[16640];
  int b = blockIdx.x;

  if (b < 512) {
    // ---------------- router ----------------
    int tid = threadIdx.x, lane = tid & 63, wv = tid >> 6;
    float (*sP)[8] = (float(*)[8])smem;
    int   (*sC)[8] = (int(*)[8])(smem + 128);
    float pacc[8]; int cacc[8];
    #pragma unroll
    for (int e = 0; e < 8; ++e) { pacc[e] = 0.f; cacc[e] = 0; }

    #pragma unroll 1
    for (int it = 0; it < 4; ++it) {
      int t = b * 16 + wv * 4 + it;
      const float4* xr = (const float4*)(x + (size_t)t * DIM);
      float acc[8];
      #pragma unroll
      for (int e = 0; e < 8; ++e) acc[e] = 0.f;
      #pragma unroll 1
      for (int i = 0; i < 8; ++i) {
        int j = i * 64 + lane;
        float4 v = xr[j];
        ushort4 o; o.x = f2bf(v.x); o.y = f2bf(v.y); o.z = f2bf(v.z); o.w = f2bf(v.w);
        *(ushort4*)(xb + (size_t)t * DIM + (size_t)j * 4) = o;
        const float* rr = rw + (size_t)j * 32;
        #pragma unroll
        for (int c = 0; c < 4; ++c) {
          float xv = (&v.x)[c];
          const float4* r4 = (const float4*)(rr + c * 8);
          float4 q0 = r4[0], q1 = r4[1];
          acc[0] += xv * q0.x; acc[1] += xv * q0.y; acc[2] += xv * q0.z; acc[3] += xv * q0.w;
          acc[4] += xv * q1.x; acc[5] += xv * q1.y; acc[6] += xv * q1.z; acc[7] += xv * q1.w;
        }
      }
      #pragma unroll
      for (int off = 32; off; off >>= 1) {
        #pragma unroll
        for (int e = 0; e < 8; ++e) acc[e] += __shfl_xor(acc[e], off);
      }
      float m = acc[0];
      #pragma unroll
      for (int e = 1; e < 8; ++e) m = fmaxf(m, acc[e]);
      float p[8], s = 0.f;
      #pragma unroll
      for (int e = 0; e < 8; ++e) { p[e] = __expf(acc[e] - m); s += p[e]; }
      float inv = 1.f / s;
      int i1 = 0; float p1v = p[0];
      #pragma unroll
      for (int e = 1; e < 8; ++e) if (p[e] > p1v) { p1v = p[e]; i1 = e; }
      int i2 = -1; float p2v = -1.f;
      #pragma unroll
      for (int e = 0; e < 8; ++e) if (e != i1 && p[e] > p2v) { p2v = p[e]; i2 = e; }
      float w1 = p1v / (p1v + p2v);
      if (lane == 0) {
        topi[t] = i1 | (i2 << 8);
        topw[t] = w1;
        #pragma unroll
        for (int e = 0; e < 8; ++e) pacc[e] += p[e] * inv;
        cacc[i1]++; cacc[i2]++;
      }
    }
    if (lane == 0) {
      #pragma unroll
      for (int e = 0; e < 8; ++e) { sP[wv][e] = pacc[e]; sC[wv][e] = cacc[e]; }
    }
    __syncthreads();
    if (tid < 8) {
      float ps = sP[0][tid] + sP[1][tid] + sP[2][tid] + sP[3][tid];
      int   cs = sC[0][tid] + sC[1][tid] + sC[2][tid] + sC[3][tid];
      atomicAdd(&cnt[tid], cs);
      atomicAdd(&psum[tid], (unsigned long long)((double)ps * 1099511627776.0));
    }
  } else if (b < 11776) {
    // ---------------- pack_gu: rows 0-63 gate, 64-127 up ----------------
    int q_ = b - 512;
    int j = q_ & 63, rest = q_ >> 6;
    int tn = rest % 22, e = rest / 22;
    float (*tg)[65] = (float(*)[65])smem;
    float (*tu)[65] = (float(*)[65])(smem + 8320);
    int t = threadIdx.x;
    const float* gs = wg + ((size_t)e * DIM + j * 32) * FFN + tn * 64;
    const float* us = wu + ((size_t)e * DIM + j * 32) * FFN + tn * 64;
    #pragma unroll
    for (int k2 = 0; k2 < 2; ++k2) {
      int idx = t + k2 * 256;
      int kk = idx >> 4, fq = idx & 15;
      *(float4*)&tg[kk][fq * 4] = *(const float4*)(gs + (size_t)kk * FFN + fq * 4);
      *(float4*)&tu[kk][fq * 4] = *(const float4*)(us + (size_t)kk * FFN + fq * 4);
    }
    __syncthreads();
    char* dst = p1 + ((size_t)((e * 22 + tn) * 64 + j)) * 8192;
    #pragma unroll
    for (int k2 = 0; k2 < 2; ++k2) {
      int L = t + k2 * 256;
      int q = L >> 3, v = (L & 7) ^ (q & 7);
      int r = 2 * q + (v >> 2), s = v & 3;
      const float* col = (r < 64) ? &tg[s * 8][r] : &tu[s * 8][r - 64];
      ushort u8[8];
      #pragma unroll
      for (int i = 0; i < 8; ++i) u8[i] = f2bf(col[i * 65]);
      *(ushort4*)(dst + (size_t)L * 16) = *(ushort4*)&u8[0];
      *(ushort4*)(dst + (size_t)L * 16 + 8) = *(ushort4*)&u8[4];
    }
  } else {
    // ---------------- pack_d: rows = 128 d-cols ----------------
    int q_ = b - 11776;
    int j = q_ % 44, rest = q_ / 44;
    int tn = rest & 15, e = rest >> 4;
    float (*t2)[129] = (float(*)[129])smem;
    int t = threadIdx.x;
    const float* src = wd + ((size_t)e * FFN + j * 32) * DIM + tn * 128;
    #pragma unroll
    for (int k2 = 0; k2 < 4; ++k2) {
      int idx = t + k2 * 256;
      int kk = idx >> 5, dq = idx & 31;
      *(float4*)&t2[kk][dq * 4] = *(const float4*)(src + (size_t)kk * DIM + dq * 4);
    }
    __syncthreads();
    char* dst = p2 + ((size_t)((e * 16 + tn) * 44 + j)) * 8192;
    #pragma unroll
    for (int k2 = 0; k2 < 2; ++k2) {
      int L = t + k2 * 256;
      int q = L >> 3, v = (L & 7) ^ (q & 7);
      int r = 2 * q + (v >> 2), s = v & 3;
      ushort u8[8];
      #pragma unroll
      for (int i = 0; i < 8; ++i) u8[i] = f2bf(t2[s * 8 + i][r]);
      *(ushort4*)(dst + (size_t)L * 16) = *(ushort4*)&u8[0];
      *(ushort4*)(dst + (size_t)L * 16 + 8) = *(ushort4*)&u8[4];
    }
  }
}

// ---------------- placement (scan fused: prefix computed locally) ----------------
__global__ __launch_bounds__(256) void place_kernel(
    const int* __restrict__ topi, int* __restrict__ stats,
    const unsigned long long* __restrict__ psum,
    int* __restrict__ lpk, int2* __restrict__ tpos, float* __restrict__ aux_out)
{
  int cnt[8], pre[8];
  int acc = 0;
  #pragma unroll
  for (int e = 0; e < 8; ++e) { cnt[e] = stats[e]; pre[e] = acc; acc += cnt[e]; }

  if (blockIdx.x == 0 && threadIdx.x == 0) {
    int tb = 0;
    for (int e = 0; e < 8; ++e) {
      stats[16 + e] = pre[e];
      stats[24 + e] = tb;
      tb += (cnt[e] + 127) >> 7;
    }
    stats[32] = tb;
    double s = 0.0;
    for (int e = 0; e < 8; ++e)
      s += (double)cnt[e] * ((double)psum[e] * (1.0 / 1099511627776.0));
    aux_out[0] = (float)(4.0 * s / ((double)N_TOK * (double)N_TOK));
  }

  int t = blockIdx.x * 256 + threadIdx.x;
  if (t >= N_TOK) return;
  int pk = topi[t];
  int e1 = pk & 0xff, e2 = (pk >> 8) & 0xff;
  int p1 = pre[e1] + atomicAdd(&stats[8 + e1], 1);
  lpk[p1] = t;
  int p2 = pre[e2] + atomicAdd(&stats[8 + e2], 1);
  lpk[p2] = t;
  tpos[t] = make_int2(p1, p2);
}

// ---------------- gather bf16 tokens into chunk-image layout (x4 split) ----------------
__global__ __launch_bounds__(256) void gather_x_kernel(
    const ushort* __restrict__ xb, const int* __restrict__ lpk,
    const int* __restrict__ stats, char* __restrict__ xgp)
{
  int b = blockIdx.x;
  int tile = b >> 2;
  if (tile >= stats[32]) return;
  int e = 0;
  #pragma unroll
  for (int k = 1; k < 8; ++k) if (tile >= stats[24 + k]) e = k;
  int tloc = tile - stats[24 + e];
  int abase = stats[16 + e], Me = stats[e];
  int quad = b & 3;
  int lane = threadIdx.x & 63, wv = threadIdx.x >> 6;
  char* base = xgp + (size_t)tile * 64 * 8192;
  #pragma unroll 1
  for (int r = quad * 32 + wv; r < quad * 32 + 32; r += 4) {
    int lrow = tloc * 128 + r;
    bool valid = lrow < Me;
    const char* src = (const char*)xb + (valid ? (size_t)lpk[abase + lrow] * (DIM * 2) : 0);
    int q = r >> 1;
    #pragma unroll
    for (int it = 0; it < 4; ++it) {
      int c16 = it * 64 + lane;
      int j = c16 >> 2, s = c16 & 3;
      uint4 v;
      if (valid) v = *(const uint4*)(src + c16 * 16);
      else       v = make_uint4(0, 0, 0, 0);
      int p = (((r & 1) << 2) | s) ^ (q & 7);
      *(uint4*)(base + (size_t)j * 8192 + q * 128 + p * 16) = v;
    }
  }
}

// =====================================================================
// GEMM core: 256x128 tile (A = 2 adjacent 128-row images, B = 1 image),
// BK=32, 4 waves of 64 rows x 128 B-rows each.
// NEW: 3-slot LDS ring (72KB), prefetch depth 2, vmcnt(12)/6/0 — gives
// the memory system ~2 iterations (~2500 cyc) to service each chunk's
// 48KB instead of 1 (the depth-1 vmcnt wait was the residual stall).
// Counted lgkmcnt split (4 then 0) retained. 2 blocks/CU (144KB LDS).
// Slot safety: iter j writes slot (j+2)%3 == (j-1)%3, whose readers all
// drained (own-wave lgkmcnt(0)) before iter j-1's end barrier.
// XCD-locality: bid&7 -> XCD -> expert; within XCD: tm outer, tn fast.
// =====================================================================

#define GSTAGE(J, BUF) do { \
  size_t go_ = (size_t)(J) * 8192 + wv * 2048 + lane * 16; \
  int d_ = (BUF) * 24576 + wv * 2048; \
  gload16(aP0 + go_,        sm + d_); \
  gload16(aP0 + go_ + 1024, sm + d_ + 1024); \
  gload16(aP1 + go_,        sm + d_ + 8192); \
  gload16(aP1 + go_ + 1024, sm + d_ + 8192 + 1024); \
  gload16(bP + go_,         sm + d_ + 16384); \
  gload16(bP + go_ + 1024,  sm + d_ + 16384 + 1024); \
} while (0)

#define KLOOP(NCH) \
  GSTAGE(0, 0); \
  GSTAGE(1, 1); \
  { int cur = 0, st = 2; \
  _Pragma("unroll 1") \
  for (int j = 0; j < (NCH); ++j) { \
    if (j + 2 < (NCH)) { \
      GSTAGE(j + 2, st); \
      asm volatile("s_waitcnt vmcnt(12)" ::: "memory"); \
    } else if (j + 2 == (NCH)) { \
      asm volatile("s_waitcnt vmcnt(6)" ::: "memory"); \
    } else { \
      asm volatile("s_waitcnt vmcnt(0)" ::: "memory"); \
    } \
    BAR(); \
    int sb = cur * 24576; \
    int4v va[4], vb[8]; \
    _Pragma("unroll") for (int n = 0; n < 4; ++n) vb[n] = dsread(sb + adB[n]); \
    _Pragma("unroll") for (int m = 0; m < 4; ++m) va[m] = dsread(sb + adA[m]); \
    _Pragma("unroll") for (int n = 4; n < 8; ++n) vb[n] = dsread(sb + adB[n]); \
    asm volatile("s_waitcnt lgkmcnt(4)" ::: "memory"); \
    __builtin_amdgcn_sched_barrier(0); \
    __builtin_amdgcn_s_setprio(1); \
    _Pragma("unroll") for (int m = 0; m < 4; ++m) \
      _Pragma("unroll") for (int n = 0; n < 4; ++n) \
        acc[m][n] = MFMA16(BC(va[m]), BC(vb[n]), acc[m][n]); \
    __builtin_amdgcn_s_setprio(0); \
    asm volatile("s_waitcnt lgkmcnt(0)" ::: "memory"); \
    __builtin_amdgcn_sched_barrier(0); \
    __builtin_amdgcn_s_setprio(1); \
    _Pragma("unroll") for (int m = 0; m < 4; ++m) \
      _Pragma("unroll") for (int n = 4; n < 8; ++n) \
        acc[m][n] = MFMA16(BC(va[m]), BC(vb[n]), acc[m][n]); \
    __builtin_amdgcn_s_setprio(0); \
    BAR(); \
    cur = (cur == 2) ? 0 : cur + 1; \
    st  = (st  == 2) ? 0 : st  + 1; \
  } }

// GEMM1: A = 256 tokens (2 images), B = {gate,up} image (rows 0-63 g, 64-127 u
// per 64 f-cols). Wave owns 64 tokens x all 128 B-rows -> SiLU in-register.
__global__ __launch_bounds__(256, 2) void gemm_gu_kernel(
    const char* __restrict__ xgp, const char* __restrict__ p1,
    const int* __restrict__ stats, char* __restrict__ hp)
{
  int bid = blockIdx.x;
  int e = bid & 7;
  int Ll = bid >> 3;
  int tm = Ll / 22, tn = Ll % 22;
  int Me = stats[e];
  if (tm * 256 >= Me) return;
  int tb = stats[24 + e];

  __shared__ char sm[73728];
  int tid = threadIdx.x, lane = tid & 63, wv = tid >> 6;
  const char* aP0 = xgp + (size_t)(tb + tm * 2) * 64 * 8192;
  const char* aP1 = aP0 + 64 * 8192;
  const char* bP = p1 + (size_t)((e * 22 + tn) * 64) * 8192;

  int s = lane >> 4;
  int adA[4], adB[8];
  #pragma unroll
  for (int m = 0; m < 4; ++m) {
    int row = wv * 64 + m * 16 + (lane & 15);
    adA[m] = (row >> 7) * 8192 + swz(row & 127, s);
  }
  #pragma unroll
  for (int n = 0; n < 8; ++n) adB[n] = 16384 + swz(n * 16 + (lane & 15), s);

  f32x4 acc[4][8];
  #pragma unroll
  for (int m = 0; m < 4; ++m)
    #pragma unroll
    for (int n = 0; n < 8; ++n) acc[m][n] = (f32x4){0, 0, 0, 0};

  KLOOP(64);

  // epilogue: gate = acc[m][n], up = acc[m][n+4] (same f-col) -> in-register SiLU.
  int r0 = (lane >> 4) * 4, cl = lane & 15;
  #pragma unroll
  for (int m = 0; m < 4; ++m) {
    #pragma unroll
    for (int r = 0; r < 4; ++r) {
      int row = wv * 64 + m * 16 + r0 + r;
      if (tm * 256 + row < Me) {
        char* hb = hp + (size_t)(tb + tm * 2 + (row >> 7)) * 44 * 8192;
        int lr = row & 127;
        int q = lr >> 1;
        #pragma unroll
        for (int n = 0; n < 4; ++n) {
          float g = acc[m][n][r];
          float u = acc[m][n + 4][r];
          float hv = g * u / (1.f + __expf(-g));
          int f = tn * 64 + n * 16 + cl;
          int j2 = f >> 5, s2 = (f >> 3) & 3, i2 = f & 7;
          int p = (((lr & 1) << 2) | s2) ^ (q & 7);
          *(ushort*)(hb + (size_t)j2 * 8192 + q * 128 + p * 16 + i2 * 2) = f2bf(hv);
        }
      }
    }
  }
}

// GEMM2: A = h (2 images), B = down image (128 d-cols); dense bf16 store to eo.
__global__ __launch_bounds__(256, 2) void gemm_down_kernel(
    const char* __restrict__ hp, const char* __restrict__ p2,
    const int* __restrict__ stats, ushort* __restrict__ eo)
{
  int bid = blockIdx.x;
  int e = bid & 7;
  int Ll = bid >> 3;
  int tm = Ll >> 4, tn = Ll & 15;
  int Me = stats[e];
  if (tm * 256 >= Me) return;
  int tb = stats[24 + e], abase = stats[16 + e];

  __shared__ char sm[73728];
  int tid = threadIdx.x, lane = tid & 63, wv = tid >> 6;
  const char* aP0 = hp + (size_t)(tb + tm * 2) * 44 * 8192;
  const char* aP1 = aP0 + 44 * 8192;
  const char* bP = p2 + (size_t)((e * 16 + tn) * 44) * 8192;

  int s = lane >> 4;
  int adA[4], adB[8];
  #pragma unroll
  for (int m = 0; m < 4; ++m) {
    int row = wv * 64 + m * 16 + (lane & 15);
    adA[m] = (row >> 7) * 8192 + swz(row & 127, s);
  }
  #pragma unroll
  for (int n = 0; n < 8; ++n) adB[n] = 16384 + swz(n * 16 + (lane & 15), s);

  f32x4 acc[4][8];
  #pragma unroll
  for (int m = 0; m < 4; ++m)
    #pragma unroll
    for (int n = 0; n < 8; ++n) acc[m][n] = (f32x4){0, 0, 0, 0};

  KLOOP(44);

  int c0 = lane & 15, r0 = (lane >> 4) * 4;
  #pragma unroll
  for (int m = 0; m < 4; ++m) {
    #pragma unroll
    for (int r = 0; r < 4; ++r) {
      int lrow = tm * 256 + wv * 64 + m * 16 + r0 + r;
      if (lrow < Me) {
        ushort* dst = eo + (size_t)(abase + lrow) * DIM + tn * 128 + c0;
        #pragma unroll
        for (int n = 0; n < 8; ++n) dst[n * 16] = f2bf(acc[m][n][r]);
      }
    }
  }
}

// ---------------- combine: out[t] = w1*eo[p1] + w2*eo[p2] (bf16 partials) ----------------
__global__ __launch_bounds__(256) void combine_kernel(
    const ushort* __restrict__ eo, const int2* __restrict__ tpos,
    const float* __restrict__ topw, float* __restrict__ out)
{
  int t = blockIdx.x;
  int2 tp = tpos[t];
  float w1 = topw[t], w2 = 1.f - w1;
  const uint4* r1 = (const uint4*)(eo + (size_t)tp.x * DIM);
  const uint4* r2 = (const uint4*)(eo + (size_t)tp.y * DIM);
  float4* o = (float4*)(out + (size_t)t * DIM);
  int i = threadIdx.x;
  uint4 a = r1[i], b = r2[i];
  float4 c0, c1;
  c0.x = w1 * blo(a.x) + w2 * blo(b.x);  c0.y = w1 * bhi(a.x) + w2 * bhi(b.x);
  c0.z = w1 * blo(a.y) + w2 * blo(b.y);  c0.w = w1 * bhi(a.y) + w2 * bhi(b.y);
  c1.x = w1 * blo(a.z) + w2 * blo(b.z);  c1.y = w1 * bhi(a.z) + w2 * bhi(b.z);
  c1.z = w1 * blo(a.w) + w2 * blo(b.w);  c1.w = w1 * bhi(a.w) + w2 * bhi(b.w);
  o[i * 2] = c0;
  o[i * 2 + 1] = c1;
}

extern "C" void kernel_launch(void* const* d_in, const int* in_sizes, int n_in,
                              void* d_out, int out_size, void* d_ws, size_t ws_size,
                              hipStream_t stream)
{
  const float* x  = (const float*)d_in[0];
  const float* rw = (const float*)d_in[1];
  const float* wg = (const float*)d_in[2];
  const float* wu = (const float*)d_in[3];
  const float* wd = (const float*)d_in[4];
  float* out = (float*)d_out;

  char* ws = (char*)d_ws;
  ushort* xb   = (ushort*)(ws + XB_OFF);
  char*   hp   = ws + HP_OFF;
  char*   xgp  = ws + XGP_OFF;
  ushort* eo   = (ushort*)(ws + EO_OFF);
  char*   p1   = ws + P1_OFF;
  char*   p2   = ws + P2_OFF;
  int*    lpk  = (int*)(ws + LPK_OFF);
  int*    topi = (int*)(ws + TI_OFF);
  float*  topw = (float*)(ws + TW_OFF);
  int2*   tpos = (int2*)(ws + TP_OFF);
  int*    stats = (int*)(ws + ST_OFF);
  unsigned long long* psum = (unsigned long long*)(ws + ST_OFF + 192);

  hipMemsetAsync(ws + ST_OFF, 0, 256, stream);

  prep_kernel<<<17408, 256, 0, stream>>>(x, rw, xb, topi, topw, stats, psum,
                                         wg, wu, wd, p1, p2);
  place_kernel<<<32, 256, 0, stream>>>(topi, stats, psum, lpk, tpos,
                                       out + (size_t)out_size - 1);

  gather_x_kernel<<<544, 256, 0, stream>>>(xb, lpk, stats, xgp);

  gemm_gu_kernel<<<2816, 256, 0, stream>>>(xgp, p1, stats, hp);
  gemm_down_kernel<<<2048, 256, 0, stream>>>(hp, p2, stats, eo);

  combine_kernel<<<8192, 256, 0, stream>>>(eo, tpos, topw, out);
}